// Round 14
// baseline (249.180 us; speedup 1.0000x reference)
//
#include <hip/hip_runtime.h>

#define BATCH 32
#define NRr 32
#define NFf 128
#define NHh 64
#define NFHh 64
#define TI 4

__device__ __forceinline__ float dot4(float4 a, float4 b) {
    return fmaf(a.x, b.x, fmaf(a.y, b.y, fmaf(a.z, b.z, a.w * b.w)));
}

// ---------------------------------------------------------------------------
// intra v8: 288 blocks, CH=32 everywhere. rh/fh blocks emit pre_y56 in a
// LIGHT tail (R9 recipe: no hoisted weight arrays). Register discipline:
// out-phase hc-loop is `#pragma unroll 1` so its 16xfloat4 w2r block is not
// live across iterations — keeps body+tail under the 128-VGPR line (the
// fully-unrolled body + tail combination spilled to 256 in R3/R10).
// ---------------------------------------------------------------------------
__global__ __launch_bounds__(256) void intra_kernel(
    const float* __restrict__ robot, const float* __restrict__ frontier,
    const float* __restrict__ rhist, const float* __restrict__ fhist,
    const float* __restrict__ Wq, const float* __restrict__ bq,
    const float* __restrict__ Wk, const float* __restrict__ bk,
    const float* __restrict__ Wv, const float* __restrict__ bv,
    const float* __restrict__ Wn1, const float* __restrict__ bn1,
    const float* __restrict__ Wn2, const float* __restrict__ bn2,
    const float* __restrict__ We1,
    float* __restrict__ o_robot, float* __restrict__ o_frontier,
    float* __restrict__ o_rh, float* __restrict__ o_fh,
    float* __restrict__ w5, float* __restrict__ yv5,
    float* __restrict__ w6, float* __restrict__ yv6)
{
    __shared__ __align__(16) float sXc[1024];
    __shared__ __align__(16) float sQ[1024];    // q; later out rows (tail)
    __shared__ __align__(16) float sAgg[1024];
    __shared__ __align__(16) float sS[4224];    // scores, pitch N+4
    __shared__ __align__(16) float sKT[4128];   // K^T [32][129]; tail: yk [32][33]
    __shared__ __align__(16) float sVT[8192];   // V [N][32], then T [32][256]

    const int blk = blockIdx.x, tid = threadIdx.x;
    const float* xin; float* xout; int N, lgN, b, chunk;
    float* wOut = nullptr; float* yvOut = nullptr;
    if (blk < 32)       { xin=robot;    xout=o_robot;    N=32;  lgN=5; b=blk;          chunk=0; }
    else if (blk < 160) { xin=frontier; xout=o_frontier; N=128; lgN=7; b=(blk-32)>>2;  chunk=(blk-32)&3; }
    else if (blk < 224) { xin=rhist;    xout=o_rh;       N=64;  lgN=6; b=(blk-160)>>1; chunk=(blk-160)&1; wOut=w5; yvOut=yv5; }
    else                { xin=fhist;    xout=o_fh;       N=64;  lgN=6; b=(blk-224)>>1; chunk=(blk-224)&1; wOut=w6; yvOut=yv6; }
    const bool isPre = (wOut != nullptr);
    const int P = N + 4;
    const float* xb = xin + (size_t)b * N * 32;
    const int r0 = chunk << 5;
    const int d = tid & 31;

    {
        int idx = tid;
        #pragma unroll
        for (int it = 0; it < 4; ++it, idx += 256)
            sXc[idx] = xb[(r0 << 5) + idx];
    }

    // K^T, V for all N rows; weight rows hoisted (fits in body alone)
    {
        const float4* wk4 = (const float4*)(Wk + (d << 5));
        const float4* wv4 = (const float4*)(Wv + (d << 5));
        float4 wk[8], wv[8];
        #pragma unroll
        for (int k = 0; k < 8; ++k) { wk[k] = wk4[k]; wv[k] = wv4[k]; }
        const float bkd = bk[d], bvd = bv[d];
        for (int idx = tid; idx < (N << 5); idx += 256) {
            int j = idx >> 5;
            const float4* xr = (const float4*)(xb + (j << 5));
            float aK = bkd, aV = bvd;
            #pragma unroll
            for (int k = 0; k < 8; ++k) {
                float4 xv = xr[k];
                aK += dot4(wk[k], xv);
                aV += dot4(wv[k], xv);
            }
            sKT[d * 129 + j] = aK;
            sVT[(j << 5) + d] = aV;
        }
    }
    __syncthreads();

    {
        const float4* wq4 = (const float4*)(Wq + (d << 5));
        float4 wq[8];
        #pragma unroll
        for (int k = 0; k < 8; ++k) wq[k] = wq4[k];
        const float bqd = bq[d];
        int idx = tid;
        #pragma unroll
        for (int it = 0; it < 4; ++it, idx += 256) {
            int r = idx >> 5;
            const float4* xr = (const float4*)(sXc + (r << 5));
            float a = bqd;
            #pragma unroll
            for (int k = 0; k < 8; ++k) a += dot4(wq[k], xr[k]);
            sQ[idx] = a;
        }
    }
    __syncthreads();

    for (int idx = tid; idx < (N << 5); idx += 256) {
        int r = idx >> lgN, j = idx & (N - 1);
        const float* qr = sQ + (r << 5);
        float a = 0.f;
        #pragma unroll
        for (int e = 0; e < 32; ++e) a = fmaf(qr[e], sKT[e * 129 + j], a);
        sS[r * P + j] = a;
    }
    __syncthreads();

    {
        int r = tid >> 3, l = tid & 7;
        float* row = sS + r * P;
        float m = -1e30f;
        for (int j = l; j < N; j += 8) m = fmaxf(m, row[j]);
        m = fmaxf(m, __shfl_xor(m, 4));
        m = fmaxf(m, __shfl_xor(m, 2));
        m = fmaxf(m, __shfl_xor(m, 1));
        float s = 0.f;
        for (int j = l; j < N; j += 8) { float ev = __expf(row[j] - m); row[j] = ev; s += ev; }
        s += __shfl_xor(s, 4); s += __shfl_xor(s, 2); s += __shfl_xor(s, 1);
        float inv = 1.0f / s;
        for (int j = l; j < N; j += 8) row[j] *= inv;
    }
    __syncthreads();

    {
        int idx = tid;
        #pragma unroll
        for (int it = 0; it < 4; ++it, idx += 256) {
            int r = idx >> 5;
            const float* er = sS + r * P;
            float a = 0.f;
            for (int j = 0; j < N; ++j) a = fmaf(er[j], sVT[(j << 5) + d], a);
            sAgg[idx] = a;
        }
    }
    __syncthreads();

    float* sT = sVT;
    {
        const float4* w14 = (const float4*)(Wn1 + (tid << 6));
        float4 w1r[16];
        #pragma unroll
        for (int k = 0; k < 16; ++k) w1r[k] = w14[k];
        const float b1 = bn1[tid];
        #pragma unroll 1
        for (int r = 0; r < 32; ++r) {
            const float4* xr = (const float4*)(sXc + (r << 5));
            const float4* ar = (const float4*)(sAgg + (r << 5));
            float a = b1;
            #pragma unroll
            for (int k = 0; k < 8; ++k) a += dot4(w1r[k], xr[k]);
            #pragma unroll
            for (int k = 0; k < 8; ++k) a += dot4(w1r[8 + k], ar[k]);
            sT[(r << 8) + tid] = fmaxf(a, 0.f);
        }
    }
    __syncthreads();

    // out = x + T @ Wn2^T + bn2; hc loop NOT unrolled (register discipline)
    {
        const int rg = tid >> 5;
        float acc[4] = {0.f, 0.f, 0.f, 0.f};
        #pragma unroll 1
        for (int hc = 0; hc < 4; ++hc) {
            const float4* w24 = (const float4*)(Wn2 + (d << 8) + (hc << 6));
            float4 w2r[16];
            #pragma unroll
            for (int k = 0; k < 16; ++k) w2r[k] = w24[k];
            #pragma unroll
            for (int p = 0; p < 4; ++p) {
                int r = rg + (p << 3);
                const float4* tr = (const float4*)(sT + (r << 8) + (hc << 6));
                float a = 0.f;
                #pragma unroll
                for (int k = 0; k < 16; ++k) a += dot4(w2r[k], tr[k]);
                acc[p] += a;
            }
        }
        const float b2 = bn2[d];
        #pragma unroll
        for (int p = 0; p < 4; ++p) {
            int r = rg + (p << 3);
            float v = sXc[(r << 5) + d] + b2 + acc[p];
            xout[((size_t)b * N << 5) + ((r0 + r) << 5) + d] = v;
            if (isPre) sQ[(r << 5) + d] = v;   // keep out rows for tail
        }
    }

    // ---- light fused pre_y tail (rh/fh only; N=64, 32 rows) — R9 recipe ----
    if (isPre) {
        __syncthreads();
        {   // yk -> sKT[r*33+d], yv -> global; weights read per-iteration
            const float4* wk4 = (const float4*)(Wk + (d << 5));
            const float4* wv4 = (const float4*)(Wv + (d << 5));
            const float bkd = bk[d], bvd = bv[d];
            const int rg = tid >> 5;
            #pragma unroll 1
            for (int p = 0; p < 4; ++p) {
                int r = rg + (p << 3);
                const float4* orow = (const float4*)(sQ + (r << 5));
                float aK = bkd, aV = bvd;
                #pragma unroll
                for (int k = 0; k < 8; ++k) {
                    float4 ov = orow[k];
                    aK += dot4(wk4[k], ov);
                    aV += dot4(wv4[k], ov);
                }
                sKT[r * 33 + d] = aK;
                yvOut[(((size_t)(b * N + r0 + r)) << 5) + d] = aV;
            }
        }
        __syncthreads();
        {   // w rows: thread h = tid, 32 j's in 4 chunks of 8; wT packed store
            const float* w1 = We1 + tid * 65 + 32;
            #pragma unroll 1
            for (int rc = 0; rc < 4; ++rc) {
                float acc[8] = {0,0,0,0,0,0,0,0};
                #pragma unroll
                for (int e = 0; e < 32; ++e) {
                    float we = w1[e];
                    #pragma unroll
                    for (int jl = 0; jl < 8; ++jl)
                        acc[jl] = fmaf(we, sKT[(rc * 8 + jl) * 33 + e], acc[jl]);
                }
                float* wbase = wOut + (((size_t)b * 64 + (tid >> 2)) * 64 + r0 + (rc << 3)) * 4 + (tid & 3);
                #pragma unroll
                for (int jl = 0; jl < 8; ++jl)
                    wbase[jl << 2] = acc[jl];
            }
        }
    }
}

// ---------------------------------------------------------------------------
// inter v7 (R13, proven 50.9 µs): TI=4, no sYV tile (yv read from global,
// L2-resident), LDS 19.9 KB -> 8 blocks/CU. wT layout:
// ((b*64+h/4)*Ny + j)*4 + h%4. Stage-B blocks emit w/yv for the next stage.
// ---------------------------------------------------------------------------
__global__ __launch_bounds__(256) void inter_main_kernel(
    const float* __restrict__ xA, int NxA, const float* __restrict__ wA, const float* __restrict__ yvA,
    int NyA, const float* __restrict__ disA, float* __restrict__ outA, float* __restrict__ eA,
    float* __restrict__ wPreA, float* __restrict__ yvPreA, int nBlkA,
    const float* __restrict__ xB, int NxB, const float* __restrict__ wB, const float* __restrict__ yvB,
    int NyB, const float* __restrict__ disB, float* __restrict__ outB, float* __restrict__ eB,
    float* __restrict__ wPreB, float* __restrict__ yvPreB,
    const float* __restrict__ Wq, const float* __restrict__ bq,
    const float* __restrict__ Wk, const float* __restrict__ bk,
    const float* __restrict__ Wv, const float* __restrict__ bv,
    const float* __restrict__ We1, const float* __restrict__ be1,
    const float* __restrict__ We2,
    const float* __restrict__ Wn1, const float* __restrict__ bn1,
    const float* __restrict__ Wn2, const float* __restrict__ bn2)
{
    __shared__ __align__(16) float sX[128];
    __shared__ __align__(16) float sQ[128];      // q; later out rows (tail)
    __shared__ __align__(16) float sAgg[128];
    __shared__ __align__(16) float sDis[512];    // [4][128]
    __shared__ __align__(16) float sC[256];
    __shared__ __align__(16) float sW2[256];
    __shared__ __align__(16) float sS[512];      // scores/e; tail: yk [4][33]
    __shared__ __align__(16) float sUT[1024];    // u (ph2-3), then T (ph7-8)
    __shared__ __align__(16) float sPR[2048];    // partials (ph3), red (ph8)

    const int blk = blockIdx.x, tid = threadIdx.x;
    const float* x; int Nx; const float* w; const float* yv; int Ny;
    const float* dis; float* outp; float* ep; float* wPre; float* yvPre; int idx;
    if (blk < nBlkA) { x=xA; Nx=NxA; w=wA; yv=yvA; Ny=NyA; dis=disA; outp=outA; ep=eA; wPre=wPreA; yvPre=yvPreA; idx=blk; }
    else             { x=xB; Nx=NxB; w=wB; yv=yvB; Ny=NyB; dis=disB; outp=outB; ep=eB; wPre=wPreB; yvPre=yvPreB; idx=blk-nBlkA; }
    const int lgNy = (Ny == 128) ? 7 : 6;
    const int tiles = Nx >> 2;
    const int b = idx / tiles, i0 = (idx - b * tiles) << 2;
    const float* xrow = x + ((size_t)(b * Nx + i0)) * 32;

    // phase 0: stage x, dis
    if (tid < 128) sX[tid] = xrow[tid];
    if (tid < Ny) {
        int il = tid >> (lgNy - 2), jq = tid & ((Ny >> 2) - 1);
        ((float4*)sDis)[(il << 5) + jq] =
            ((const float4*)(dis + ((size_t)(b * Nx + i0 + il)) * Ny))[jq];
    }
    __syncthreads();

    // phase 1: Q
    if (tid < 128) {
        int il = tid >> 5, dd = tid & 31;
        const float4* wq4 = (const float4*)(Wq + (dd << 5));
        const float4* xr = (const float4*)(sX + (il << 5));
        float a = bq[dd];
        #pragma unroll
        for (int k = 0; k < 8; ++k) a += dot4(wq4[k], xr[k]);
        sQ[tid] = a;
    }
    __syncthreads();

    // phase 2: u, c, w2
    {
        const float* w1 = We1 + tid * 65;
        const float b1 = be1[tid];
        float acc[TI];
        #pragma unroll
        for (int il = 0; il < TI; ++il) acc[il] = b1;
        #pragma unroll
        for (int e = 0; e < 32; ++e) {
            float we = w1[e];
            #pragma unroll
            for (int il = 0; il < TI; ++il)
                acc[il] = fmaf(we, sQ[(il << 5) + e], acc[il]);
        }
        #pragma unroll
        for (int il = 0; il < TI; ++il) sUT[(il << 8) + tid] = acc[il];
        sC[tid] = w1[64];
        sW2[tid] = We2[tid];
    }
    __syncthreads();

    // phase 3: scores; wave wv owns h-quarter, lane = j, all 4 i's
    const int wv = tid >> 6, lane = tid & 63;
    {
        const int hc0 = wv << 4;
        const float4* wT4 = (const float4*)w + (size_t)(b * 64) * Ny;
        const float4* c4p = (const float4*)sC;
        const float4* p4p = (const float4*)sW2;
        if (Ny == 64) {
            float dv[TI];
            #pragma unroll
            for (int il = 0; il < TI; ++il) dv[il] = sDis[(il << 7) + lane];
            float acc[TI] = {0.f, 0.f, 0.f, 0.f};
            #pragma unroll
            for (int t = 0; t < 16; ++t) {
                int hc = hc0 + t;
                float4 w4 = wT4[((size_t)hc << 6) + lane];
                float4 c4 = c4p[hc], p4 = p4p[hc];
                #pragma unroll
                for (int il = 0; il < TI; ++il) {
                    float4 u4 = ((const float4*)(sUT + (il << 8)))[hc];
                    acc[il] = fmaf(p4.x, fmaxf(fmaf(c4.x, dv[il], u4.x + w4.x), 0.f), acc[il]);
                    acc[il] = fmaf(p4.y, fmaxf(fmaf(c4.y, dv[il], u4.y + w4.y), 0.f), acc[il]);
                    acc[il] = fmaf(p4.z, fmaxf(fmaf(c4.z, dv[il], u4.z + w4.z), 0.f), acc[il]);
                    acc[il] = fmaf(p4.w, fmaxf(fmaf(c4.w, dv[il], u4.w + w4.w), 0.f), acc[il]);
                }
            }
            #pragma unroll
            for (int il = 0; il < TI; ++il)
                sPR[(wv << 9) + (il << 7) + lane] = acc[il];
        } else {
            float dv0[TI], dv1[TI];
            #pragma unroll
            for (int il = 0; il < TI; ++il) {
                dv0[il] = sDis[(il << 7) + lane];
                dv1[il] = sDis[(il << 7) + 64 + lane];
            }
            float acc0[TI] = {0.f, 0.f, 0.f, 0.f};
            float acc1[TI] = {0.f, 0.f, 0.f, 0.f};
            #pragma unroll
            for (int t = 0; t < 16; ++t) {
                int hc = hc0 + t;
                float4 wa = wT4[((size_t)hc << 7) + lane];
                float4 wb = wT4[((size_t)hc << 7) + 64 + lane];
                float4 c4 = c4p[hc], p4 = p4p[hc];
                #pragma unroll
                for (int il = 0; il < TI; ++il) {
                    float4 u4 = ((const float4*)(sUT + (il << 8)))[hc];
                    acc0[il] = fmaf(p4.x, fmaxf(fmaf(c4.x, dv0[il], u4.x + wa.x), 0.f), acc0[il]);
                    acc0[il] = fmaf(p4.y, fmaxf(fmaf(c4.y, dv0[il], u4.y + wa.y), 0.f), acc0[il]);
                    acc0[il] = fmaf(p4.z, fmaxf(fmaf(c4.z, dv0[il], u4.z + wa.z), 0.f), acc0[il]);
                    acc0[il] = fmaf(p4.w, fmaxf(fmaf(c4.w, dv0[il], u4.w + wa.w), 0.f), acc0[il]);
                    acc1[il] = fmaf(p4.x, fmaxf(fmaf(c4.x, dv1[il], u4.x + wb.x), 0.f), acc1[il]);
                    acc1[il] = fmaf(p4.y, fmaxf(fmaf(c4.y, dv1[il], u4.y + wb.y), 0.f), acc1[il]);
                    acc1[il] = fmaf(p4.z, fmaxf(fmaf(c4.z, dv1[il], u4.z + wb.z), 0.f), acc1[il]);
                    acc1[il] = fmaf(p4.w, fmaxf(fmaf(c4.w, dv1[il], u4.w + wb.w), 0.f), acc1[il]);
                }
            }
            #pragma unroll
            for (int il = 0; il < TI; ++il) {
                sPR[(wv << 9) + (il << 7) + lane] = acc0[il];
                sPR[(wv << 9) + (il << 7) + 64 + lane] = acc1[il];
            }
        }
    }
    __syncthreads();

    // reduce h-quarter partials into sS
    for (int k = tid; k < (TI << lgNy); k += 256) {
        int il = k >> lgNy, j = k & (Ny - 1);
        int o = (il << 7) + j;
        sS[o] = sPR[o] + sPR[512 + o] + sPR[1024 + o] + sPR[1536 + o];
    }
    __syncthreads();

    // phase 4: softmax per wave + edge write
    {
        float v0 = sS[(wv << 7) + lane];
        float v1 = (Ny == 128) ? sS[(wv << 7) + 64 + lane] : -1e30f;
        float m = fmaxf(v0, v1);
        #pragma unroll
        for (int msk = 32; msk; msk >>= 1) m = fmaxf(m, __shfl_xor(m, msk));
        float e0 = __expf(v0 - m);
        float e1 = (Ny == 128) ? __expf(v1 - m) : 0.f;
        float s = e0 + e1;
        #pragma unroll
        for (int msk = 32; msk; msk >>= 1) s += __shfl_xor(s, msk);
        float inv = 1.0f / s;
        e0 *= inv; e1 *= inv;
        sS[(wv << 7) + lane] = e0;
        if (Ny == 128) sS[(wv << 7) + 64 + lane] = e1;
        if (ep) {
            float* erow = ep + ((size_t)(b * Nx + i0 + wv)) * Ny;
            erow[lane] = e0;
            if (Ny == 128) erow[64 + lane] = e1;
        }
    }

    // phase 5: agg = e @ yv (global yv — L2-resident, coalesced per j-row)
    {
        const int dd = lane & 31, jg = lane >> 5;
        float p = 0.f;
        for (int j = jg; j < Ny; j += 2)
            p = fmaf(sS[(wv << 7) + j], yv[(((size_t)(b * Ny + j)) << 5) + dd], p);
        p += __shfl_xor(p, 32);
        if (jg == 0) sAgg[(wv << 5) + dd] = p;
    }
    __syncthreads();

    // phase 7: node-MLP hidden (T overlays u)
    {
        const float4* w14 = (const float4*)(Wn1 + (tid << 6));
        const float b1 = bn1[tid];
        float acc[TI];
        #pragma unroll
        for (int il = 0; il < TI; ++il) acc[il] = b1;
        #pragma unroll
        for (int k = 0; k < 8; ++k) {
            float4 wa = w14[k];
            #pragma unroll
            for (int il = 0; il < TI; ++il)
                acc[il] += dot4(wa, ((const float4*)(sX + (il << 5)))[k]);
        }
        #pragma unroll
        for (int k = 0; k < 8; ++k) {
            float4 wb = w14[8 + k];
            #pragma unroll
            for (int il = 0; il < TI; ++il)
                acc[il] += dot4(wb, ((const float4*)(sAgg + (il << 5)))[k]);
        }
        __syncthreads();
        #pragma unroll
        for (int il = 0; il < TI; ++il) sUT[(il << 8) + tid] = fmaxf(acc[il], 0.f);
    }
    __syncthreads();

    // phase 8: out = x + T @ Wn2^T + bn2
    {
        const int hg = tid >> 5, dd = tid & 31;
        const float4* w24 = (const float4*)(Wn2 + (dd << 8) + (hg << 5));
        float4 w2r[8];
        #pragma unroll
        for (int k = 0; k < 8; ++k) w2r[k] = w24[k];
        float p[TI] = {0.f, 0.f, 0.f, 0.f};
        #pragma unroll
        for (int k = 0; k < 8; ++k) {
            #pragma unroll
            for (int il = 0; il < TI; ++il)
                p[il] += dot4(w2r[k], ((const float4*)(sUT + (il << 8) + (hg << 5)))[k]);
        }
        #pragma unroll
        for (int il = 0; il < TI; ++il) sPR[(hg << 7) + (il << 5) + dd] = p[il];
    }
    __syncthreads();
    if (tid < 128) {
        int il = tid >> 5, dd = tid & 31;
        float a = bn2[dd] + sX[tid];
        #pragma unroll
        for (int hg = 0; hg < 8; ++hg) a += sPR[(hg << 7) + tid];
        outp[((size_t)(b * Nx + i0 + il)) * 32 + dd] = a;
        if (wPre) sQ[tid] = a;     // keep out rows for tail (sQ dead since ph2)
    }

    // ---- light fused pre tail (stage-6 blocks): w/yv for the next stage ----
    if (wPre) {
        __syncthreads();
        {   // yk -> sS[il*33+dd] (sS dead), yv -> global
            int t = tid & 127, il = t >> 5, dd = t & 31;
            const float4* wm4 = (const float4*)(((tid < 128) ? Wk : Wv) + (dd << 5));
            const float4* orow = (const float4*)(sQ + (il << 5));
            float a = (tid < 128) ? bk[dd] : bv[dd];
            #pragma unroll
            for (int k = 0; k < 8; ++k) a += dot4(wm4[k], orow[k]);
            if (tid < 128) sS[il * 33 + dd] = a;
            else yvPre[(((size_t)(b * Nx + i0 + il)) << 5) + dd] = a;
        }
        __syncthreads();
        {   // w rows for 4 j's; wT packed store (next-stage Ny == Nx here)
            const float* w1 = We1 + tid * 65 + 32;
            float acc[4] = {0.f, 0.f, 0.f, 0.f};
            #pragma unroll
            for (int e = 0; e < 32; ++e) {
                float we = w1[e];
                #pragma unroll
                for (int il = 0; il < 4; ++il)
                    acc[il] = fmaf(we, sS[il * 33 + e], acc[il]);
            }
            float* wbase = wPre + (((size_t)b * 64 + (tid >> 2)) * Nx + i0) * 4 + (tid & 3);
            #pragma unroll
            for (int il = 0; il < 4; ++il)
                wbase[il << 2] = acc[il];
        }
    }
}

// ---------------------------------------------------------------------------
extern "C" void kernel_launch(void* const* d_in, const int* in_sizes, int n_in,
                              void* d_out, int out_size, void* d_ws, size_t ws_size,
                              hipStream_t stream) {
    const float* robot          = (const float*)d_in[0];
    const float* frontier       = (const float*)d_in[1];
    const float* rh             = (const float*)d_in[2];
    const float* fh             = (const float*)d_in[3];
    const float* robot_frontier = (const float*)d_in[4];
    const float* robot_past     = (const float*)d_in[5];
    const float* frontier_past  = (const float*)d_in[6];
    const float* Wq  = (const float*)d_in[7];  const float* bq  = (const float*)d_in[8];
    const float* Wk  = (const float*)d_in[9];  const float* bk  = (const float*)d_in[10];
    const float* Wv  = (const float*)d_in[11]; const float* bv  = (const float*)d_in[12];
    const float* Wn1 = (const float*)d_in[13]; const float* bn1 = (const float*)d_in[14];
    const float* Wn2 = (const float*)d_in[15]; const float* bn2 = (const float*)d_in[16];
    const float* We1 = (const float*)d_in[17]; const float* be1 = (const float*)d_in[18];
    const float* We2 = (const float*)d_in[19];

    float* out = (float*)d_out;
    float* out_robot    = out;            // 32*32*32   = 32768
    float* out_frontier = out + 32768;    // 32*128*32  = 131072
    float* out_rh       = out + 163840;   // 32*64*32   = 65536
    float* out_fh       = out + 229376;   // 32*64*32   = 65536
    float* out_edge     = out + 294912;   // 32*32*128  = 131072

    float* W = (float*)d_ws;
    float* robot1 = W;                 // 32768
    float* robot2 = W + 32768;         // 32768
    float* nf     = W + 65536;         // 131072
    float* w5     = W + 196608;        // 524288 (wT layout)
    float* yv5    = W + 720896;        // 65536
    float* w6     = W + 786432;        // 524288 (wT layout)
    float* yv6    = W + 1310720;       // 65536
    float* w7     = W + 1376256;       // 1048576 (wT layout)
    float* yv7    = W + 2424832;       // 131072

    // A: four intra-attentions + fused pre_y56 tails (rh/fh blocks)
    intra_kernel<<<288, 256, 0, stream>>>(robot, frontier, rh, fh,
        Wq, bq, Wk, bk, Wv, bv, Wn1, bn1, Wn2, bn2, We1,
        robot1, out_frontier, out_rh, out_fh, w5, yv5, w6, yv6);

    // B: inter5 (robot1 x rh1) + inter6 (frontier1 x fh1, fused pre_y7 tail)
    inter_main_kernel<<<1280, 256, 0, stream>>>(
        robot1, NRr, w5, yv5, NHh, robot_past, robot2,
        (float*)nullptr, (float*)nullptr, (float*)nullptr, BATCH * (NRr / TI),
        out_frontier, NFf, w6, yv6, NFHh, frontier_past, nf,
        (float*)nullptr, w7, yv7,
        Wq, bq, Wk, bk, Wv, bv, We1, be1, We2, Wn1, bn1, Wn2, bn2);

    // C: inter7 (robot2 x new_frontier) -> final robot + edge
    inter_main_kernel<<<256, 256, 0, stream>>>(
        robot2, NRr, w7, yv7, NFf, robot_frontier, out_robot, out_edge,
        (float*)nullptr, (float*)nullptr, BATCH * (NRr / TI),
        robot2, NRr, w7, yv7, NFf, robot_frontier, out_robot, out_edge,
        (float*)nullptr, (float*)nullptr,
        Wq, bq, Wk, bk, Wv, bv, We1, be1, We2, Wn1, bn1, Wn2, bn2);
}

// Round 15
// 209.942 us; speedup vs baseline: 1.1869x; 1.1869x over previous
//
#include <hip/hip_runtime.h>

#define BATCH 32
#define NRr 32
#define NFf 128
#define NHh 64
#define NFHh 64
#define TI 4

__device__ __forceinline__ float dot4(float4 a, float4 b) {
    return fmaf(a.x, b.x, fmaf(a.y, b.y, fmaf(a.z, b.z, a.w * b.w)));
}

// ---------------------------------------------------------------------------
// intra (R11 exact): 288 blocks, CH=32. No tail — every fusion attempt broke
// it (R3/R10: 256-VGPR spill; R14: unroll-1 ILP loss). Pitch N+4 softmax.
// ---------------------------------------------------------------------------
__global__ __launch_bounds__(256) void intra_kernel(
    const float* __restrict__ robot, const float* __restrict__ frontier,
    const float* __restrict__ rhist, const float* __restrict__ fhist,
    const float* __restrict__ Wq, const float* __restrict__ bq,
    const float* __restrict__ Wk, const float* __restrict__ bk,
    const float* __restrict__ Wv, const float* __restrict__ bv,
    const float* __restrict__ Wn1, const float* __restrict__ bn1,
    const float* __restrict__ Wn2, const float* __restrict__ bn2,
    float* __restrict__ o_robot, float* __restrict__ o_frontier,
    float* __restrict__ o_rh, float* __restrict__ o_fh)
{
    __shared__ __align__(16) float sXc[1024];
    __shared__ __align__(16) float sQ[1024];
    __shared__ __align__(16) float sAgg[1024];
    __shared__ __align__(16) float sS[4224];
    __shared__ __align__(16) float sKT[4128];
    __shared__ __align__(16) float sVT[8192];

    const int blk = blockIdx.x, tid = threadIdx.x;
    const float* xin; float* xout; int N, lgN, b, chunk;
    if (blk < 32)       { xin=robot;    xout=o_robot;    N=32;  lgN=5; b=blk;          chunk=0; }
    else if (blk < 160) { xin=frontier; xout=o_frontier; N=128; lgN=7; b=(blk-32)>>2;  chunk=(blk-32)&3; }
    else if (blk < 224) { xin=rhist;    xout=o_rh;       N=64;  lgN=6; b=(blk-160)>>1; chunk=(blk-160)&1; }
    else                { xin=fhist;    xout=o_fh;       N=64;  lgN=6; b=(blk-224)>>1; chunk=(blk-224)&1; }

    const int P = N + 4;
    const float* xb = xin + (size_t)b * N * 32;
    const int r0 = chunk << 5;
    const int d = tid & 31;

    {
        int idx = tid;
        #pragma unroll
        for (int it = 0; it < 4; ++it, idx += 256)
            sXc[idx] = xb[(r0 << 5) + idx];
    }

    {
        const float4* wk4 = (const float4*)(Wk + (d << 5));
        const float4* wv4 = (const float4*)(Wv + (d << 5));
        float4 wk[8], wv[8];
        #pragma unroll
        for (int k = 0; k < 8; ++k) { wk[k] = wk4[k]; wv[k] = wv4[k]; }
        const float bkd = bk[d], bvd = bv[d];
        for (int idx = tid; idx < (N << 5); idx += 256) {
            int j = idx >> 5;
            const float4* xr = (const float4*)(xb + (j << 5));
            float aK = bkd, aV = bvd;
            #pragma unroll
            for (int k = 0; k < 8; ++k) {
                float4 xv = xr[k];
                aK += dot4(wk[k], xv);
                aV += dot4(wv[k], xv);
            }
            sKT[d * 129 + j] = aK;
            sVT[(j << 5) + d] = aV;
        }
    }
    __syncthreads();

    {
        const float4* wq4 = (const float4*)(Wq + (d << 5));
        float4 wq[8];
        #pragma unroll
        for (int k = 0; k < 8; ++k) wq[k] = wq4[k];
        const float bqd = bq[d];
        int idx = tid;
        #pragma unroll
        for (int it = 0; it < 4; ++it, idx += 256) {
            int r = idx >> 5;
            const float4* xr = (const float4*)(sXc + (r << 5));
            float a = bqd;
            #pragma unroll
            for (int k = 0; k < 8; ++k) a += dot4(wq[k], xr[k]);
            sQ[idx] = a;
        }
    }
    __syncthreads();

    for (int idx = tid; idx < (N << 5); idx += 256) {
        int r = idx >> lgN, j = idx & (N - 1);
        const float* qr = sQ + (r << 5);
        float a = 0.f;
        #pragma unroll
        for (int e = 0; e < 32; ++e) a = fmaf(qr[e], sKT[e * 129 + j], a);
        sS[r * P + j] = a;
    }
    __syncthreads();

    {
        int r = tid >> 3, l = tid & 7;
        float* row = sS + r * P;
        float m = -1e30f;
        for (int j = l; j < N; j += 8) m = fmaxf(m, row[j]);
        m = fmaxf(m, __shfl_xor(m, 4));
        m = fmaxf(m, __shfl_xor(m, 2));
        m = fmaxf(m, __shfl_xor(m, 1));
        float s = 0.f;
        for (int j = l; j < N; j += 8) { float ev = __expf(row[j] - m); row[j] = ev; s += ev; }
        s += __shfl_xor(s, 4); s += __shfl_xor(s, 2); s += __shfl_xor(s, 1);
        float inv = 1.0f / s;
        for (int j = l; j < N; j += 8) row[j] *= inv;
    }
    __syncthreads();

    {
        int idx = tid;
        #pragma unroll
        for (int it = 0; it < 4; ++it, idx += 256) {
            int r = idx >> 5;
            const float* er = sS + r * P;
            float a = 0.f;
            for (int j = 0; j < N; ++j) a = fmaf(er[j], sVT[(j << 5) + d], a);
            sAgg[idx] = a;
        }
    }
    __syncthreads();

    float* sT = sVT;
    {
        const float4* w14 = (const float4*)(Wn1 + (tid << 6));
        float4 w1r[16];
        #pragma unroll
        for (int k = 0; k < 16; ++k) w1r[k] = w14[k];
        const float b1 = bn1[tid];
        for (int r = 0; r < 32; ++r) {
            const float4* xr = (const float4*)(sXc + (r << 5));
            const float4* ar = (const float4*)(sAgg + (r << 5));
            float a = b1;
            #pragma unroll
            for (int k = 0; k < 8; ++k) a += dot4(w1r[k], xr[k]);
            #pragma unroll
            for (int k = 0; k < 8; ++k) a += dot4(w1r[8 + k], ar[k]);
            sT[(r << 8) + tid] = fmaxf(a, 0.f);
        }
    }
    __syncthreads();

    {
        const int rg = tid >> 5;
        float acc[4] = {0.f, 0.f, 0.f, 0.f};
        #pragma unroll
        for (int hc = 0; hc < 4; ++hc) {
            const float4* w24 = (const float4*)(Wn2 + (d << 8) + (hc << 6));
            float4 w2r[16];
            #pragma unroll
            for (int k = 0; k < 16; ++k) w2r[k] = w24[k];
            #pragma unroll
            for (int p = 0; p < 4; ++p) {
                int r = rg + (p << 3);
                const float4* tr = (const float4*)(sT + (r << 8) + (hc << 6));
                float a = 0.f;
                #pragma unroll
                for (int k = 0; k < 16; ++k) a += dot4(w2r[k], tr[k]);
                acc[p] += a;
            }
        }
        const float b2 = bn2[d];
        #pragma unroll
        for (int p = 0; p < 4; ++p) {
            int r = rg + (p << 3);
            xout[((size_t)b * N << 5) + ((r0 + r) << 5) + d] = sXc[(r << 5) + d] + b2 + acc[p];
        }
    }
}

// ---------------------------------------------------------------------------
// pre_y (R11 exact): block = 8 j's. Emits yv (row-major) and w transposed
// packed: wT flat = ((b*64 + h/4)*Ny + j)*4 + h%4
// ---------------------------------------------------------------------------
__global__ __launch_bounds__(256) void pre_y_kernel(
    const float* __restrict__ yA, int NyA, float* __restrict__ wOutA, float* __restrict__ yvOutA, int nBlkA,
    const float* __restrict__ yB, int NyB, float* __restrict__ wOutB, float* __restrict__ yvOutB,
    const float* __restrict__ Wk, const float* __restrict__ bk,
    const float* __restrict__ Wv, const float* __restrict__ bv,
    const float* __restrict__ We1)
{
    __shared__ __align__(16) float sY[256], sK[256];
    const int blk = blockIdx.x, tid = threadIdx.x;
    const float* y; int Ny; float* wOut; float* yvOut; int idx;
    if (blk < nBlkA) { y=yA; Ny=NyA; wOut=wOutA; yvOut=yvOutA; idx=blk; }
    else             { y=yB; Ny=NyB; wOut=wOutB; yvOut=yvOutB; idx=blk-nBlkA; }
    const int chunks = Ny >> 3;
    const int b = idx / chunks, j0 = (idx - b * chunks) << 3;

    sY[tid] = y[((size_t)(b * Ny + j0)) * 32 + tid];
    __syncthreads();

    {
        int jl = tid >> 5, dd = tid & 31;
        const float4* wk4 = (const float4*)(Wk + (dd << 5));
        const float4* wv4 = (const float4*)(Wv + (dd << 5));
        const float4* yr = (const float4*)(sY + (jl << 5));
        float aK = bk[dd], aV = bv[dd];
        #pragma unroll
        for (int k = 0; k < 8; ++k) {
            float4 yv4 = yr[k];
            aK += dot4(wk4[k], yv4);
            aV += dot4(wv4[k], yv4);
        }
        sK[(jl << 5) + dd] = aK;
        yvOut[((size_t)(b * Ny + j0 + jl)) * 32 + dd] = aV;
    }
    __syncthreads();

    {
        const float* w1 = We1 + tid * 65 + 32;
        float acc[8] = {0,0,0,0,0,0,0,0};
        #pragma unroll
        for (int e = 0; e < 32; ++e) {
            float we = w1[e];
            #pragma unroll
            for (int jl = 0; jl < 8; ++jl)
                acc[jl] = fmaf(we, sK[(jl << 5) + e], acc[jl]);
        }
        float* wbase = wOut + (((size_t)b * 64 + (tid >> 2)) * Ny + j0) * 4 + (tid & 3);
        #pragma unroll
        for (int jl = 0; jl < 8; ++jl)
            wbase[jl << 2] = acc[jl];
    }
}

// ---------------------------------------------------------------------------
// inter v5 (R11 exact): block = (b, 4 i's). Phase 3 splits h across the 4
// waves (partials exact: score linear after ReLU). wT layout:
// ((b*64+h/4)*Ny + j)*4 + h%4. Stage-B blocks emit w/yv for the next stage.
// ---------------------------------------------------------------------------
__global__ __launch_bounds__(256) void inter_main_kernel(
    const float* __restrict__ xA, int NxA, const float* __restrict__ wA, const float* __restrict__ yvA,
    int NyA, const float* __restrict__ disA, float* __restrict__ outA, float* __restrict__ eA,
    float* __restrict__ wPreA, float* __restrict__ yvPreA, int nBlkA,
    const float* __restrict__ xB, int NxB, const float* __restrict__ wB, const float* __restrict__ yvB,
    int NyB, const float* __restrict__ disB, float* __restrict__ outB, float* __restrict__ eB,
    float* __restrict__ wPreB, float* __restrict__ yvPreB,
    const float* __restrict__ Wq, const float* __restrict__ bq,
    const float* __restrict__ Wk, const float* __restrict__ bk,
    const float* __restrict__ Wv, const float* __restrict__ bv,
    const float* __restrict__ We1, const float* __restrict__ be1,
    const float* __restrict__ We2,
    const float* __restrict__ Wn1, const float* __restrict__ bn1,
    const float* __restrict__ Wn2, const float* __restrict__ bn2)
{
    __shared__ __align__(16) float sX[128];
    __shared__ __align__(16) float sQ[128];      // q; later out rows (tail)
    __shared__ __align__(16) float sAgg[128];
    __shared__ __align__(16) float sDis[512];    // [4][128]
    __shared__ __align__(16) float sC[256];
    __shared__ __align__(16) float sW2[256];
    __shared__ __align__(16) float sS[512];      // scores/e; tail: yk [4][33]
    __shared__ __align__(16) float sUT[1024];    // u (ph2-3), then T (ph7-8)
    __shared__ __align__(16) float sPR[2048];    // partials (ph3), red (ph8)
    __shared__ __align__(16) float sYV[4096];    // yv tile [Ny][32]

    const int blk = blockIdx.x, tid = threadIdx.x;
    const float* x; int Nx; const float* w; const float* yv; int Ny;
    const float* dis; float* outp; float* ep; float* wPre; float* yvPre; int idx;
    if (blk < nBlkA) { x=xA; Nx=NxA; w=wA; yv=yvA; Ny=NyA; dis=disA; outp=outA; ep=eA; wPre=wPreA; yvPre=yvPreA; idx=blk; }
    else             { x=xB; Nx=NxB; w=wB; yv=yvB; Ny=NyB; dis=disB; outp=outB; ep=eB; wPre=wPreB; yvPre=yvPreB; idx=blk-nBlkA; }
    const int lgNy = (Ny == 128) ? 7 : 6;
    const int tiles = Nx >> 2;
    const int b = idx / tiles, i0 = (idx - b * tiles) << 2;
    const float* xrow = x + ((size_t)(b * Nx + i0)) * 32;

    // phase 0: stage x, dis, yv
    if (tid < 128) sX[tid] = xrow[tid];
    if (tid < Ny) {
        int il = tid >> (lgNy - 2), jq = tid & ((Ny >> 2) - 1);
        ((float4*)sDis)[(il << 5) + jq] =
            ((const float4*)(dis + ((size_t)(b * Nx + i0 + il)) * Ny))[jq];
    }
    {
        const float4* yv4 = (const float4*)(yv + ((size_t)(b * Ny) << 5));
        for (int k = tid; k < (Ny << 3); k += 256)
            ((float4*)sYV)[k] = yv4[k];
    }
    __syncthreads();

    // phase 1: Q
    if (tid < 128) {
        int il = tid >> 5, dd = tid & 31;
        const float4* wq4 = (const float4*)(Wq + (dd << 5));
        const float4* xr = (const float4*)(sX + (il << 5));
        float a = bq[dd];
        #pragma unroll
        for (int k = 0; k < 8; ++k) a += dot4(wq4[k], xr[k]);
        sQ[tid] = a;
    }
    __syncthreads();

    // phase 2: u, c, w2
    {
        const float* w1 = We1 + tid * 65;
        const float b1 = be1[tid];
        float acc[TI];
        #pragma unroll
        for (int il = 0; il < TI; ++il) acc[il] = b1;
        #pragma unroll
        for (int e = 0; e < 32; ++e) {
            float we = w1[e];
            #pragma unroll
            for (int il = 0; il < TI; ++il)
                acc[il] = fmaf(we, sQ[(il << 5) + e], acc[il]);
        }
        #pragma unroll
        for (int il = 0; il < TI; ++il) sUT[(il << 8) + tid] = acc[il];
        sC[tid] = w1[64];
        sW2[tid] = We2[tid];
    }
    __syncthreads();

    // phase 3: scores; wave wv owns h-quarter, lane = j, all 4 i's
    const int wv = tid >> 6, lane = tid & 63;
    {
        const int hc0 = wv << 4;
        const float4* wT4 = (const float4*)w + (size_t)(b * 64) * Ny;
        const float4* c4p = (const float4*)sC;
        const float4* p4p = (const float4*)sW2;
        if (Ny == 64) {
            float dv[TI];
            #pragma unroll
            for (int il = 0; il < TI; ++il) dv[il] = sDis[(il << 7) + lane];
            float acc[TI] = {0.f, 0.f, 0.f, 0.f};
            #pragma unroll
            for (int t = 0; t < 16; ++t) {
                int hc = hc0 + t;
                float4 w4 = wT4[((size_t)hc << 6) + lane];
                float4 c4 = c4p[hc], p4 = p4p[hc];
                #pragma unroll
                for (int il = 0; il < TI; ++il) {
                    float4 u4 = ((const float4*)(sUT + (il << 8)))[hc];
                    acc[il] = fmaf(p4.x, fmaxf(fmaf(c4.x, dv[il], u4.x + w4.x), 0.f), acc[il]);
                    acc[il] = fmaf(p4.y, fmaxf(fmaf(c4.y, dv[il], u4.y + w4.y), 0.f), acc[il]);
                    acc[il] = fmaf(p4.z, fmaxf(fmaf(c4.z, dv[il], u4.z + w4.z), 0.f), acc[il]);
                    acc[il] = fmaf(p4.w, fmaxf(fmaf(c4.w, dv[il], u4.w + w4.w), 0.f), acc[il]);
                }
            }
            #pragma unroll
            for (int il = 0; il < TI; ++il)
                sPR[(wv << 9) + (il << 7) + lane] = acc[il];
        } else {
            float dv0[TI], dv1[TI];
            #pragma unroll
            for (int il = 0; il < TI; ++il) {
                dv0[il] = sDis[(il << 7) + lane];
                dv1[il] = sDis[(il << 7) + 64 + lane];
            }
            float acc0[TI] = {0.f, 0.f, 0.f, 0.f};
            float acc1[TI] = {0.f, 0.f, 0.f, 0.f};
            #pragma unroll
            for (int t = 0; t < 16; ++t) {
                int hc = hc0 + t;
                float4 wa = wT4[((size_t)hc << 7) + lane];
                float4 wb = wT4[((size_t)hc << 7) + 64 + lane];
                float4 c4 = c4p[hc], p4 = p4p[hc];
                #pragma unroll
                for (int il = 0; il < TI; ++il) {
                    float4 u4 = ((const float4*)(sUT + (il << 8)))[hc];
                    acc0[il] = fmaf(p4.x, fmaxf(fmaf(c4.x, dv0[il], u4.x + wa.x), 0.f), acc0[il]);
                    acc0[il] = fmaf(p4.y, fmaxf(fmaf(c4.y, dv0[il], u4.y + wa.y), 0.f), acc0[il]);
                    acc0[il] = fmaf(p4.z, fmaxf(fmaf(c4.z, dv0[il], u4.z + wa.z), 0.f), acc0[il]);
                    acc0[il] = fmaf(p4.w, fmaxf(fmaf(c4.w, dv0[il], u4.w + wa.w), 0.f), acc0[il]);
                    acc1[il] = fmaf(p4.x, fmaxf(fmaf(c4.x, dv1[il], u4.x + wb.x), 0.f), acc1[il]);
                    acc1[il] = fmaf(p4.y, fmaxf(fmaf(c4.y, dv1[il], u4.y + wb.y), 0.f), acc1[il]);
                    acc1[il] = fmaf(p4.z, fmaxf(fmaf(c4.z, dv1[il], u4.z + wb.z), 0.f), acc1[il]);
                    acc1[il] = fmaf(p4.w, fmaxf(fmaf(c4.w, dv1[il], u4.w + wb.w), 0.f), acc1[il]);
                }
            }
            #pragma unroll
            for (int il = 0; il < TI; ++il) {
                sPR[(wv << 9) + (il << 7) + lane] = acc0[il];
                sPR[(wv << 9) + (il << 7) + 64 + lane] = acc1[il];
            }
        }
    }
    __syncthreads();

    // reduce h-quarter partials into sS
    for (int k = tid; k < (TI << lgNy); k += 256) {
        int il = k >> lgNy, j = k & (Ny - 1);
        int o = (il << 7) + j;
        sS[o] = sPR[o] + sPR[512 + o] + sPR[1024 + o] + sPR[1536 + o];
    }
    __syncthreads();

    // phase 4: softmax per wave + edge write
    {
        float v0 = sS[(wv << 7) + lane];
        float v1 = (Ny == 128) ? sS[(wv << 7) + 64 + lane] : -1e30f;
        float m = fmaxf(v0, v1);
        #pragma unroll
        for (int msk = 32; msk; msk >>= 1) m = fmaxf(m, __shfl_xor(m, msk));
        float e0 = __expf(v0 - m);
        float e1 = (Ny == 128) ? __expf(v1 - m) : 0.f;
        float s = e0 + e1;
        #pragma unroll
        for (int msk = 32; msk; msk >>= 1) s += __shfl_xor(s, msk);
        float inv = 1.0f / s;
        e0 *= inv; e1 *= inv;
        sS[(wv << 7) + lane] = e0;
        if (Ny == 128) sS[(wv << 7) + 64 + lane] = e1;
        if (ep) {
            float* erow = ep + ((size_t)(b * Nx + i0 + wv)) * Ny;
            erow[lane] = e0;
            if (Ny == 128) erow[64 + lane] = e1;
        }
    }

    // phase 5: agg = e @ yv (LDS)
    {
        const int dd = lane & 31, jg = lane >> 5;
        float p = 0.f;
        for (int j = jg; j < Ny; j += 2)
            p = fmaf(sS[(wv << 7) + j], sYV[(j << 5) + dd], p);
        p += __shfl_xor(p, 32);
        if (jg == 0) sAgg[(wv << 5) + dd] = p;
    }
    __syncthreads();

    // phase 7: node-MLP hidden (T overlays u)
    {
        const float4* w14 = (const float4*)(Wn1 + (tid << 6));
        const float b1 = bn1[tid];
        float acc[TI];
        #pragma unroll
        for (int il = 0; il < TI; ++il) acc[il] = b1;
        #pragma unroll
        for (int k = 0; k < 8; ++k) {
            float4 wa = w14[k];
            #pragma unroll
            for (int il = 0; il < TI; ++il)
                acc[il] += dot4(wa, ((const float4*)(sX + (il << 5)))[k]);
        }
        #pragma unroll
        for (int k = 0; k < 8; ++k) {
            float4 wb = w14[8 + k];
            #pragma unroll
            for (int il = 0; il < TI; ++il)
                acc[il] += dot4(wb, ((const float4*)(sAgg + (il << 5)))[k]);
        }
        __syncthreads();
        #pragma unroll
        for (int il = 0; il < TI; ++il) sUT[(il << 8) + tid] = fmaxf(acc[il], 0.f);
    }
    __syncthreads();

    // phase 8: out = x + T @ Wn2^T + bn2
    {
        const int hg = tid >> 5, dd = tid & 31;
        const float4* w24 = (const float4*)(Wn2 + (dd << 8) + (hg << 5));
        float4 w2r[8];
        #pragma unroll
        for (int k = 0; k < 8; ++k) w2r[k] = w24[k];
        float p[TI] = {0.f, 0.f, 0.f, 0.f};
        #pragma unroll
        for (int k = 0; k < 8; ++k) {
            #pragma unroll
            for (int il = 0; il < TI; ++il)
                p[il] += dot4(w2r[k], ((const float4*)(sUT + (il << 8) + (hg << 5)))[k]);
        }
        #pragma unroll
        for (int il = 0; il < TI; ++il) sPR[(hg << 7) + (il << 5) + dd] = p[il];
    }
    __syncthreads();
    if (tid < 128) {
        int il = tid >> 5, dd = tid & 31;
        float a = bn2[dd] + sX[tid];
        #pragma unroll
        for (int hg = 0; hg < 8; ++hg) a += sPR[(hg << 7) + tid];
        outp[((size_t)(b * Nx + i0 + il)) * 32 + dd] = a;
        if (wPre) sQ[tid] = a;     // keep out rows for tail (sQ dead since ph2)
    }

    // ---- light fused pre tail (stage-6 blocks): w/yv for the next stage ----
    if (wPre) {
        __syncthreads();
        {   // yk -> sS[il*33+dd] (sS dead), yv -> global
            int t = tid & 127, il = t >> 5, dd = t & 31;
            const float4* wm4 = (const float4*)(((tid < 128) ? Wk : Wv) + (dd << 5));
            const float4* orow = (const float4*)(sQ + (il << 5));
            float a = (tid < 128) ? bk[dd] : bv[dd];
            #pragma unroll
            for (int k = 0; k < 8; ++k) a += dot4(wm4[k], orow[k]);
            if (tid < 128) sS[il * 33 + dd] = a;
            else yvPre[(((size_t)(b * Nx + i0 + il)) << 5) + dd] = a;
        }
        __syncthreads();
        {   // w rows for 4 j's; wT packed store (next-stage Ny == Nx here)
            const float* w1 = We1 + tid * 65 + 32;
            float acc[4] = {0.f, 0.f, 0.f, 0.f};
            #pragma unroll
            for (int e = 0; e < 32; ++e) {
                float we = w1[e];
                #pragma unroll
                for (int il = 0; il < 4; ++il)
                    acc[il] = fmaf(we, sS[il * 33 + e], acc[il]);
            }
            float* wbase = wPre + (((size_t)b * 64 + (tid >> 2)) * Nx + i0) * 4 + (tid & 3);
            #pragma unroll
            for (int il = 0; il < 4; ++il)
                wbase[il << 2] = acc[il];
        }
    }
}

// ---------------------------------------------------------------------------
extern "C" void kernel_launch(void* const* d_in, const int* in_sizes, int n_in,
                              void* d_out, int out_size, void* d_ws, size_t ws_size,
                              hipStream_t stream) {
    const float* robot          = (const float*)d_in[0];
    const float* frontier       = (const float*)d_in[1];
    const float* rh             = (const float*)d_in[2];
    const float* fh             = (const float*)d_in[3];
    const float* robot_frontier = (const float*)d_in[4];
    const float* robot_past     = (const float*)d_in[5];
    const float* frontier_past  = (const float*)d_in[6];
    const float* Wq  = (const float*)d_in[7];  const float* bq  = (const float*)d_in[8];
    const float* Wk  = (const float*)d_in[9];  const float* bk  = (const float*)d_in[10];
    const float* Wv  = (const float*)d_in[11]; const float* bv  = (const float*)d_in[12];
    const float* Wn1 = (const float*)d_in[13]; const float* bn1 = (const float*)d_in[14];
    const float* Wn2 = (const float*)d_in[15]; const float* bn2 = (const float*)d_in[16];
    const float* We1 = (const float*)d_in[17]; const float* be1 = (const float*)d_in[18];
    const float* We2 = (const float*)d_in[19];

    float* out = (float*)d_out;
    float* out_robot    = out;            // 32*32*32   = 32768
    float* out_frontier = out + 32768;    // 32*128*32  = 131072
    float* out_rh       = out + 163840;   // 32*64*32   = 65536
    float* out_fh       = out + 229376;   // 32*64*32   = 65536
    float* out_edge     = out + 294912;   // 32*32*128  = 131072

    float* W = (float*)d_ws;
    float* robot1 = W;                 // 32768
    float* robot2 = W + 32768;         // 32768
    float* nf     = W + 65536;         // 131072
    float* w5     = W + 196608;        // 524288 (wT layout)
    float* yv5    = W + 720896;        // 65536
    float* w6     = W + 786432;        // 524288 (wT layout)
    float* yv6    = W + 1310720;       // 65536
    float* w7     = W + 1376256;       // 1048576 (wT layout)
    float* yv7    = W + 2424832;       // 131072

    // A: four intra-attentions (288 blocks, R6 geometry, no tail)
    intra_kernel<<<288, 256, 0, stream>>>(robot, frontier, rh, fh,
        Wq, bq, Wk, bk, Wv, bv, Wn1, bn1, Wn2, bn2,
        robot1, out_frontier, out_rh, out_fh);

    // B: y-side precompute for inter5 (y=rh1) and inter6 (y=fh1)
    pre_y_kernel<<<512, 256, 0, stream>>>(
        out_rh, NHh, w5, yv5, BATCH * NHh / 8,
        out_fh, NFHh, w6, yv6,
        Wk, bk, Wv, bv, We1);

    // C: inter5 (robot1 x rh1) + inter6 (frontier1 x fh1, fused pre_y7 tail)
    inter_main_kernel<<<1280, 256, 0, stream>>>(
        robot1, NRr, w5, yv5, NHh, robot_past, robot2,
        (float*)nullptr, (float*)nullptr, (float*)nullptr, BATCH * (NRr / TI),
        out_frontier, NFf, w6, yv6, NFHh, frontier_past, nf,
        (float*)nullptr, w7, yv7,
        Wq, bq, Wk, bk, Wv, bv, We1, be1, We2, Wn1, bn1, Wn2, bn2);

    // D: inter7 (robot2 x new_frontier) -> final robot + edge
    inter_main_kernel<<<256, 256, 0, stream>>>(
        robot2, NRr, w7, yv7, NFf, robot_frontier, out_robot, out_edge,
        (float*)nullptr, (float*)nullptr, BATCH * (NRr / TI),
        robot2, NRr, w7, yv7, NFf, robot_frontier, out_robot, out_edge,
        (float*)nullptr, (float*)nullptr,
        Wq, bq, Wk, bk, Wv, bv, We1, be1, We2, Wn1, bn1, Wn2, bn2);
}

// Round 16
// 203.986 us; speedup vs baseline: 1.2216x; 1.0292x over previous
//
#include <hip/hip_runtime.h>

#define BATCH 32
#define NRr 32
#define NFf 128
#define NHh 64
#define NFHh 64
#define TI 4

__device__ __forceinline__ float dot4(float4 a, float4 b) {
    return fmaf(a.x, b.x, fmaf(a.y, b.y, fmaf(a.z, b.z, a.w * b.w)));
}

// ---------------------------------------------------------------------------
// intra v9 (factorized): score_rj = (Wk^T q_r)·x_j  (q·bk row-const dropped —
// softmax invariant); agg_r = Wv·(e_r@x) + bv  (Σe=1). K/V matrices never
// materialized: LDS 78.8 -> 50.2 KB (3 blocks/CU), K/V phase (2N*1024 MACs)
// replaced by two 32x32 matvecs. 288 blocks, CH=32. No pre tail (R3/R10/R14).
// ---------------------------------------------------------------------------
__global__ __launch_bounds__(256) void intra_kernel(
    const float* __restrict__ robot, const float* __restrict__ frontier,
    const float* __restrict__ rhist, const float* __restrict__ fhist,
    const float* __restrict__ Wq, const float* __restrict__ bq,
    const float* __restrict__ Wk, const float* __restrict__ bk,
    const float* __restrict__ Wv, const float* __restrict__ bv,
    const float* __restrict__ Wn1, const float* __restrict__ bn1,
    const float* __restrict__ Wn2, const float* __restrict__ bn2,
    float* __restrict__ o_robot, float* __restrict__ o_frontier,
    float* __restrict__ o_rh, float* __restrict__ o_fh)
{
    __shared__ __align__(16) float sXc[1024];   // chunk x rows [32][32]
    __shared__ __align__(16) float sQ[1024];    // q [32][32]; later z [32][32]
    __shared__ __align__(16) float sQK[1024];   // Wk^T q [32][32]
    __shared__ __align__(16) float sAgg[1024];  // agg [32][32]
    __shared__ __align__(16) float sBig[8448];  // sS[32][N+4] + sXT[32][N+1]; later T[32][256]
    float* sS  = sBig;           // scores, pitch P = N+4 (max 4224)
    float* sXT = sBig + 4224;    // x^T, pitch P2 = N+1 (max 32*129 = 4128)
    float* sT  = sBig;           // T overlays sS+sXT after z phase (8192)

    const int blk = blockIdx.x, tid = threadIdx.x;
    const float* xin; float* xout; int N, lgN, b, chunk;
    if (blk < 32)       { xin=robot;    xout=o_robot;    N=32;  lgN=5; b=blk;          chunk=0; }
    else if (blk < 160) { xin=frontier; xout=o_frontier; N=128; lgN=7; b=(blk-32)>>2;  chunk=(blk-32)&3; }
    else if (blk < 224) { xin=rhist;    xout=o_rh;       N=64;  lgN=6; b=(blk-160)>>1; chunk=(blk-160)&1; }
    else                { xin=fhist;    xout=o_fh;       N=64;  lgN=6; b=(blk-224)>>1; chunk=(blk-224)&1; }

    const int P = N + 4, P2 = N + 1;   // odd pitch P2 -> conflict-free x^T
    const float* xb = xin + (size_t)b * N * 32;
    const int r0 = chunk << 5;
    const int d = tid & 31;

    // stage: chunk x rows (row-major) + ALL x rows transposed
    {
        int idx = tid;
        #pragma unroll
        for (int it = 0; it < 4; ++it, idx += 256)
            sXc[idx] = xb[(r0 << 5) + idx];
    }
    for (int idx = tid; idx < (N << 5); idx += 256) {
        int j = idx >> 5, d2 = idx & 31;
        sXT[d2 * P2 + j] = xb[idx];
    }
    __syncthreads();

    // Q for chunk rows: q_r = Wq x_r + bq (Wq row hoisted)
    {
        const float4* wq4 = (const float4*)(Wq + (d << 5));
        float4 wq[8];
        #pragma unroll
        for (int k = 0; k < 8; ++k) wq[k] = wq4[k];
        const float bqd = bq[d];
        int idx = tid;
        #pragma unroll
        for (int it = 0; it < 4; ++it, idx += 256) {
            int r = idx >> 5;
            const float4* xr = (const float4*)(sXc + (r << 5));
            float a = bqd;
            #pragma unroll
            for (int k = 0; k < 8; ++k) a += dot4(wq[k], xr[k]);
            sQ[idx] = a;
        }
    }
    __syncthreads();

    // qk_r = Wk^T q_r (column access, L1-broadcast lines)
    {
        int idx = tid;
        #pragma unroll
        for (int it = 0; it < 4; ++it, idx += 256) {
            int r = idx >> 5, e = idx & 31;
            const float* qr = sQ + (r << 5);
            float a = 0.f;
            #pragma unroll
            for (int dd2 = 0; dd2 < 32; ++dd2)
                a = fmaf(Wk[dd2 * 32 + e], qr[dd2], a);
            sQK[idx] = a;
        }
    }
    __syncthreads();

    // scores: s_rj = qk_r . x_j   (x^T rows, conflict-free)
    for (int idx = tid; idx < (N << 5); idx += 256) {
        int r = idx >> lgN, j = idx & (N - 1);
        const float* qr = sQK + (r << 5);
        float a = 0.f;
        #pragma unroll
        for (int e = 0; e < 32; ++e) a = fmaf(qr[e], sXT[e * P2 + j], a);
        sS[r * P + j] = a;
    }
    __syncthreads();

    // softmax per row: 32 rows x 8 lanes, pitch P
    {
        int r = tid >> 3, l = tid & 7;
        float* row = sS + r * P;
        float m = -1e30f;
        for (int j = l; j < N; j += 8) m = fmaxf(m, row[j]);
        m = fmaxf(m, __shfl_xor(m, 4));
        m = fmaxf(m, __shfl_xor(m, 2));
        m = fmaxf(m, __shfl_xor(m, 1));
        float s = 0.f;
        for (int j = l; j < N; j += 8) { float ev = __expf(row[j] - m); row[j] = ev; s += ev; }
        s += __shfl_xor(s, 4); s += __shfl_xor(s, 2); s += __shfl_xor(s, 1);
        float inv = 1.0f / s;
        for (int j = l; j < N; j += 8) row[j] *= inv;
    }
    __syncthreads();

    // z_r = e_r @ x  (into sQ — q dead since qk phase)
    {
        int idx = tid;
        #pragma unroll
        for (int it = 0; it < 4; ++it, idx += 256) {
            int r = idx >> 5, d2 = idx & 31;
            const float* er = sS + r * P;
            const float* xtr = sXT + d2 * P2;
            float a = 0.f;
            for (int j = 0; j < N; ++j) a = fmaf(er[j], xtr[j], a);
            sQ[idx] = a;
        }
    }
    __syncthreads();

    // agg_r = Wv z_r + bv (Wv row hoisted)
    {
        const float4* wv4 = (const float4*)(Wv + (d << 5));
        float4 wv[8];
        #pragma unroll
        for (int k = 0; k < 8; ++k) wv[k] = wv4[k];
        const float bvd = bv[d];
        int idx = tid;
        #pragma unroll
        for (int it = 0; it < 4; ++it, idx += 256) {
            int r = idx >> 5;
            const float4* zr = (const float4*)(sQ + (r << 5));
            float a = bvd;
            #pragma unroll
            for (int k = 0; k < 8; ++k) a += dot4(wv[k], zr[k]);
            sAgg[idx] = a;
        }
    }
    __syncthreads();

    // T = relu([x, agg] @ Wn1^T + bn1): thread h = tid; sT overlays sS/sXT
    {
        const float4* w14 = (const float4*)(Wn1 + (tid << 6));
        float4 w1r[16];
        #pragma unroll
        for (int k = 0; k < 16; ++k) w1r[k] = w14[k];
        const float b1 = bn1[tid];
        for (int r = 0; r < 32; ++r) {
            const float4* xr = (const float4*)(sXc + (r << 5));
            const float4* ar = (const float4*)(sAgg + (r << 5));
            float a = b1;
            #pragma unroll
            for (int k = 0; k < 8; ++k) a += dot4(w1r[k], xr[k]);
            #pragma unroll
            for (int k = 0; k < 8; ++k) a += dot4(w1r[8 + k], ar[k]);
            sT[(r << 8) + tid] = fmaxf(a, 0.f);
        }
    }
    __syncthreads();

    // out = x + T @ Wn2^T + bn2: thread (rg, d), 4 rows each, h chunked
    {
        const int rg = tid >> 5;
        float acc[4] = {0.f, 0.f, 0.f, 0.f};
        #pragma unroll
        for (int hc = 0; hc < 4; ++hc) {
            const float4* w24 = (const float4*)(Wn2 + (d << 8) + (hc << 6));
            float4 w2r[16];
            #pragma unroll
            for (int k = 0; k < 16; ++k) w2r[k] = w24[k];
            #pragma unroll
            for (int p = 0; p < 4; ++p) {
                int r = rg + (p << 3);
                const float4* tr = (const float4*)(sT + (r << 8) + (hc << 6));
                float a = 0.f;
                #pragma unroll
                for (int k = 0; k < 16; ++k) a += dot4(w2r[k], tr[k]);
                acc[p] += a;
            }
        }
        const float b2 = bn2[d];
        #pragma unroll
        for (int p = 0; p < 4; ++p) {
            int r = rg + (p << 3);
            xout[((size_t)b * N << 5) + ((r0 + r) << 5) + d] = sXc[(r << 5) + d] + b2 + acc[p];
        }
    }
}

// ---------------------------------------------------------------------------
// pre_y (R15 exact): block = 8 j's. Emits yv (row-major) and w transposed
// packed: wT flat = ((b*64 + h/4)*Ny + j)*4 + h%4
// ---------------------------------------------------------------------------
__global__ __launch_bounds__(256) void pre_y_kernel(
    const float* __restrict__ yA, int NyA, float* __restrict__ wOutA, float* __restrict__ yvOutA, int nBlkA,
    const float* __restrict__ yB, int NyB, float* __restrict__ wOutB, float* __restrict__ yvOutB,
    const float* __restrict__ Wk, const float* __restrict__ bk,
    const float* __restrict__ Wv, const float* __restrict__ bv,
    const float* __restrict__ We1)
{
    __shared__ __align__(16) float sY[256], sK[256];
    const int blk = blockIdx.x, tid = threadIdx.x;
    const float* y; int Ny; float* wOut; float* yvOut; int idx;
    if (blk < nBlkA) { y=yA; Ny=NyA; wOut=wOutA; yvOut=yvOutA; idx=blk; }
    else             { y=yB; Ny=NyB; wOut=wOutB; yvOut=yvOutB; idx=blk-nBlkA; }
    const int chunks = Ny >> 3;
    const int b = idx / chunks, j0 = (idx - b * chunks) << 3;

    sY[tid] = y[((size_t)(b * Ny + j0)) * 32 + tid];
    __syncthreads();

    {
        int jl = tid >> 5, dd = tid & 31;
        const float4* wk4 = (const float4*)(Wk + (dd << 5));
        const float4* wv4 = (const float4*)(Wv + (dd << 5));
        const float4* yr = (const float4*)(sY + (jl << 5));
        float aK = bk[dd], aV = bv[dd];
        #pragma unroll
        for (int k = 0; k < 8; ++k) {
            float4 yv4 = yr[k];
            aK += dot4(wk4[k], yv4);
            aV += dot4(wv4[k], yv4);
        }
        sK[(jl << 5) + dd] = aK;
        yvOut[((size_t)(b * Ny + j0 + jl)) * 32 + dd] = aV;
    }
    __syncthreads();

    {
        const float* w1 = We1 + tid * 65 + 32;
        float acc[8] = {0,0,0,0,0,0,0,0};
        #pragma unroll
        for (int e = 0; e < 32; ++e) {
            float we = w1[e];
            #pragma unroll
            for (int jl = 0; jl < 8; ++jl)
                acc[jl] = fmaf(we, sK[(jl << 5) + e], acc[jl]);
        }
        float* wbase = wOut + (((size_t)b * 64 + (tid >> 2)) * Ny + j0) * 4 + (tid & 3);
        #pragma unroll
        for (int jl = 0; jl < 8; ++jl)
            wbase[jl << 2] = acc[jl];
    }
}

// ---------------------------------------------------------------------------
// inter v5 (R15 exact): block = (b, 4 i's). Phase 3 splits h across the 4
// waves. wT layout: ((b*64+h/4)*Ny + j)*4 + h%4. Stage-B blocks emit w/yv
// for the next stage (light tail).
// ---------------------------------------------------------------------------
__global__ __launch_bounds__(256) void inter_main_kernel(
    const float* __restrict__ xA, int NxA, const float* __restrict__ wA, const float* __restrict__ yvA,
    int NyA, const float* __restrict__ disA, float* __restrict__ outA, float* __restrict__ eA,
    float* __restrict__ wPreA, float* __restrict__ yvPreA, int nBlkA,
    const float* __restrict__ xB, int NxB, const float* __restrict__ wB, const float* __restrict__ yvB,
    int NyB, const float* __restrict__ disB, float* __restrict__ outB, float* __restrict__ eB,
    float* __restrict__ wPreB, float* __restrict__ yvPreB,
    const float* __restrict__ Wq, const float* __restrict__ bq,
    const float* __restrict__ Wk, const float* __restrict__ bk,
    const float* __restrict__ Wv, const float* __restrict__ bv,
    const float* __restrict__ We1, const float* __restrict__ be1,
    const float* __restrict__ We2,
    const float* __restrict__ Wn1, const float* __restrict__ bn1,
    const float* __restrict__ Wn2, const float* __restrict__ bn2)
{
    __shared__ __align__(16) float sX[128];
    __shared__ __align__(16) float sQ[128];      // q; later out rows (tail)
    __shared__ __align__(16) float sAgg[128];
    __shared__ __align__(16) float sDis[512];    // [4][128]
    __shared__ __align__(16) float sC[256];
    __shared__ __align__(16) float sW2[256];
    __shared__ __align__(16) float sS[512];      // scores/e; tail: yk [4][33]
    __shared__ __align__(16) float sUT[1024];    // u (ph2-3), then T (ph7-8)
    __shared__ __align__(16) float sPR[2048];    // partials (ph3), red (ph8)
    __shared__ __align__(16) float sYV[4096];    // yv tile [Ny][32]

    const int blk = blockIdx.x, tid = threadIdx.x;
    const float* x; int Nx; const float* w; const float* yv; int Ny;
    const float* dis; float* outp; float* ep; float* wPre; float* yvPre; int idx;
    if (blk < nBlkA) { x=xA; Nx=NxA; w=wA; yv=yvA; Ny=NyA; dis=disA; outp=outA; ep=eA; wPre=wPreA; yvPre=yvPreA; idx=blk; }
    else             { x=xB; Nx=NxB; w=wB; yv=yvB; Ny=NyB; dis=disB; outp=outB; ep=eB; wPre=wPreB; yvPre=yvPreB; idx=blk-nBlkA; }
    const int lgNy = (Ny == 128) ? 7 : 6;
    const int tiles = Nx >> 2;
    const int b = idx / tiles, i0 = (idx - b * tiles) << 2;
    const float* xrow = x + ((size_t)(b * Nx + i0)) * 32;

    // phase 0: stage x, dis, yv
    if (tid < 128) sX[tid] = xrow[tid];
    if (tid < Ny) {
        int il = tid >> (lgNy - 2), jq = tid & ((Ny >> 2) - 1);
        ((float4*)sDis)[(il << 5) + jq] =
            ((const float4*)(dis + ((size_t)(b * Nx + i0 + il)) * Ny))[jq];
    }
    {
        const float4* yv4 = (const float4*)(yv + ((size_t)(b * Ny) << 5));
        for (int k = tid; k < (Ny << 3); k += 256)
            ((float4*)sYV)[k] = yv4[k];
    }
    __syncthreads();

    // phase 1: Q
    if (tid < 128) {
        int il = tid >> 5, dd = tid & 31;
        const float4* wq4 = (const float4*)(Wq + (dd << 5));
        const float4* xr = (const float4*)(sX + (il << 5));
        float a = bq[dd];
        #pragma unroll
        for (int k = 0; k < 8; ++k) a += dot4(wq4[k], xr[k]);
        sQ[tid] = a;
    }
    __syncthreads();

    // phase 2: u, c, w2
    {
        const float* w1 = We1 + tid * 65;
        const float b1 = be1[tid];
        float acc[TI];
        #pragma unroll
        for (int il = 0; il < TI; ++il) acc[il] = b1;
        #pragma unroll
        for (int e = 0; e < 32; ++e) {
            float we = w1[e];
            #pragma unroll
            for (int il = 0; il < TI; ++il)
                acc[il] = fmaf(we, sQ[(il << 5) + e], acc[il]);
        }
        #pragma unroll
        for (int il = 0; il < TI; ++il) sUT[(il << 8) + tid] = acc[il];
        sC[tid] = w1[64];
        sW2[tid] = We2[tid];
    }
    __syncthreads();

    // phase 3: scores; wave wv owns h-quarter, lane = j, all 4 i's
    const int wv = tid >> 6, lane = tid & 63;
    {
        const int hc0 = wv << 4;
        const float4* wT4 = (const float4*)w + (size_t)(b * 64) * Ny;
        const float4* c4p = (const float4*)sC;
        const float4* p4p = (const float4*)sW2;
        if (Ny == 64) {
            float dv[TI];
            #pragma unroll
            for (int il = 0; il < TI; ++il) dv[il] = sDis[(il << 7) + lane];
            float acc[TI] = {0.f, 0.f, 0.f, 0.f};
            #pragma unroll
            for (int t = 0; t < 16; ++t) {
                int hc = hc0 + t;
                float4 w4 = wT4[((size_t)hc << 6) + lane];
                float4 c4 = c4p[hc], p4 = p4p[hc];
                #pragma unroll
                for (int il = 0; il < TI; ++il) {
                    float4 u4 = ((const float4*)(sUT + (il << 8)))[hc];
                    acc[il] = fmaf(p4.x, fmaxf(fmaf(c4.x, dv[il], u4.x + w4.x), 0.f), acc[il]);
                    acc[il] = fmaf(p4.y, fmaxf(fmaf(c4.y, dv[il], u4.y + w4.y), 0.f), acc[il]);
                    acc[il] = fmaf(p4.z, fmaxf(fmaf(c4.z, dv[il], u4.z + w4.z), 0.f), acc[il]);
                    acc[il] = fmaf(p4.w, fmaxf(fmaf(c4.w, dv[il], u4.w + w4.w), 0.f), acc[il]);
                }
            }
            #pragma unroll
            for (int il = 0; il < TI; ++il)
                sPR[(wv << 9) + (il << 7) + lane] = acc[il];
        } else {
            float dv0[TI], dv1[TI];
            #pragma unroll
            for (int il = 0; il < TI; ++il) {
                dv0[il] = sDis[(il << 7) + lane];
                dv1[il] = sDis[(il << 7) + 64 + lane];
            }
            float acc0[TI] = {0.f, 0.f, 0.f, 0.f};
            float acc1[TI] = {0.f, 0.f, 0.f, 0.f};
            #pragma unroll
            for (int t = 0; t < 16; ++t) {
                int hc = hc0 + t;
                float4 wa = wT4[((size_t)hc << 7) + lane];
                float4 wb = wT4[((size_t)hc << 7) + 64 + lane];
                float4 c4 = c4p[hc], p4 = p4p[hc];
                #pragma unroll
                for (int il = 0; il < TI; ++il) {
                    float4 u4 = ((const float4*)(sUT + (il << 8)))[hc];
                    acc0[il] = fmaf(p4.x, fmaxf(fmaf(c4.x, dv0[il], u4.x + wa.x), 0.f), acc0[il]);
                    acc0[il] = fmaf(p4.y, fmaxf(fmaf(c4.y, dv0[il], u4.y + wa.y), 0.f), acc0[il]);
                    acc0[il] = fmaf(p4.z, fmaxf(fmaf(c4.z, dv0[il], u4.z + wa.z), 0.f), acc0[il]);
                    acc0[il] = fmaf(p4.w, fmaxf(fmaf(c4.w, dv0[il], u4.w + wa.w), 0.f), acc0[il]);
                    acc1[il] = fmaf(p4.x, fmaxf(fmaf(c4.x, dv1[il], u4.x + wb.x), 0.f), acc1[il]);
                    acc1[il] = fmaf(p4.y, fmaxf(fmaf(c4.y, dv1[il], u4.y + wb.y), 0.f), acc1[il]);
                    acc1[il] = fmaf(p4.z, fmaxf(fmaf(c4.z, dv1[il], u4.z + wb.z), 0.f), acc1[il]);
                    acc1[il] = fmaf(p4.w, fmaxf(fmaf(c4.w, dv1[il], u4.w + wb.w), 0.f), acc1[il]);
                }
            }
            #pragma unroll
            for (int il = 0; il < TI; ++il) {
                sPR[(wv << 9) + (il << 7) + lane] = acc0[il];
                sPR[(wv << 9) + (il << 7) + 64 + lane] = acc1[il];
            }
        }
    }
    __syncthreads();

    // reduce h-quarter partials into sS
    for (int k = tid; k < (TI << lgNy); k += 256) {
        int il = k >> lgNy, j = k & (Ny - 1);
        int o = (il << 7) + j;
        sS[o] = sPR[o] + sPR[512 + o] + sPR[1024 + o] + sPR[1536 + o];
    }
    __syncthreads();

    // phase 4: softmax per wave + edge write
    {
        float v0 = sS[(wv << 7) + lane];
        float v1 = (Ny == 128) ? sS[(wv << 7) + 64 + lane] : -1e30f;
        float m = fmaxf(v0, v1);
        #pragma unroll
        for (int msk = 32; msk; msk >>= 1) m = fmaxf(m, __shfl_xor(m, msk));
        float e0 = __expf(v0 - m);
        float e1 = (Ny == 128) ? __expf(v1 - m) : 0.f;
        float s = e0 + e1;
        #pragma unroll
        for (int msk = 32; msk; msk >>= 1) s += __shfl_xor(s, msk);
        float inv = 1.0f / s;
        e0 *= inv; e1 *= inv;
        sS[(wv << 7) + lane] = e0;
        if (Ny == 128) sS[(wv << 7) + 64 + lane] = e1;
        if (ep) {
            float* erow = ep + ((size_t)(b * Nx + i0 + wv)) * Ny;
            erow[lane] = e0;
            if (Ny == 128) erow[64 + lane] = e1;
        }
    }

    // phase 5: agg = e @ yv (LDS)
    {
        const int dd = lane & 31, jg = lane >> 5;
        float p = 0.f;
        for (int j = jg; j < Ny; j += 2)
            p = fmaf(sS[(wv << 7) + j], sYV[(j << 5) + dd], p);
        p += __shfl_xor(p, 32);
        if (jg == 0) sAgg[(wv << 5) + dd] = p;
    }
    __syncthreads();

    // phase 7: node-MLP hidden (T overlays u)
    {
        const float4* w14 = (const float4*)(Wn1 + (tid << 6));
        const float b1 = bn1[tid];
        float acc[TI];
        #pragma unroll
        for (int il = 0; il < TI; ++il) acc[il] = b1;
        #pragma unroll
        for (int k = 0; k < 8; ++k) {
            float4 wa = w14[k];
            #pragma unroll
            for (int il = 0; il < TI; ++il)
                acc[il] += dot4(wa, ((const float4*)(sX + (il << 5)))[k]);
        }
        #pragma unroll
        for (int k = 0; k < 8; ++k) {
            float4 wb = w14[8 + k];
            #pragma unroll
            for (int il = 0; il < TI; ++il)
                acc[il] += dot4(wb, ((const float4*)(sAgg + (il << 5)))[k]);
        }
        __syncthreads();
        #pragma unroll
        for (int il = 0; il < TI; ++il) sUT[(il << 8) + tid] = fmaxf(acc[il], 0.f);
    }
    __syncthreads();

    // phase 8: out = x + T @ Wn2^T + bn2
    {
        const int hg = tid >> 5, dd = tid & 31;
        const float4* w24 = (const float4*)(Wn2 + (dd << 8) + (hg << 5));
        float4 w2r[8];
        #pragma unroll
        for (int k = 0; k < 8; ++k) w2r[k] = w24[k];
        float p[TI] = {0.f, 0.f, 0.f, 0.f};
        #pragma unroll
        for (int k = 0; k < 8; ++k) {
            #pragma unroll
            for (int il = 0; il < TI; ++il)
                p[il] += dot4(w2r[k], ((const float4*)(sUT + (il << 8) + (hg << 5)))[k]);
        }
        #pragma unroll
        for (int il = 0; il < TI; ++il) sPR[(hg << 7) + (il << 5) + dd] = p[il];
    }
    __syncthreads();
    if (tid < 128) {
        int il = tid >> 5, dd = tid & 31;
        float a = bn2[dd] + sX[tid];
        #pragma unroll
        for (int hg = 0; hg < 8; ++hg) a += sPR[(hg << 7) + tid];
        outp[((size_t)(b * Nx + i0 + il)) * 32 + dd] = a;
        if (wPre) sQ[tid] = a;     // keep out rows for tail (sQ dead since ph2)
    }

    // ---- light fused pre tail (stage-6 blocks): w/yv for the next stage ----
    if (wPre) {
        __syncthreads();
        {   // yk -> sS[il*33+dd] (sS dead), yv -> global
            int t = tid & 127, il = t >> 5, dd = t & 31;
            const float4* wm4 = (const float4*)(((tid < 128) ? Wk : Wv) + (dd << 5));
            const float4* orow = (const float4*)(sQ + (il << 5));
            float a = (tid < 128) ? bk[dd] : bv[dd];
            #pragma unroll
            for (int k = 0; k < 8; ++k) a += dot4(wm4[k], orow[k]);
            if (tid < 128) sS[il * 33 + dd] = a;
            else yvPre[(((size_t)(b * Nx + i0 + il)) << 5) + dd] = a;
        }
        __syncthreads();
        {   // w rows for 4 j's; wT packed store (next-stage Ny == Nx here)
            const float* w1 = We1 + tid * 65 + 32;
            float acc[4] = {0.f, 0.f, 0.f, 0.f};
            #pragma unroll
            for (int e = 0; e < 32; ++e) {
                float we = w1[e];
                #pragma unroll
                for (int il = 0; il < 4; ++il)
                    acc[il] = fmaf(we, sS[il * 33 + e], acc[il]);
            }
            float* wbase = wPre + (((size_t)b * 64 + (tid >> 2)) * Nx + i0) * 4 + (tid & 3);
            #pragma unroll
            for (int il = 0; il < 4; ++il)
                wbase[il << 2] = acc[il];
        }
    }
}

// ---------------------------------------------------------------------------
extern "C" void kernel_launch(void* const* d_in, const int* in_sizes, int n_in,
                              void* d_out, int out_size, void* d_ws, size_t ws_size,
                              hipStream_t stream) {
    const float* robot          = (const float*)d_in[0];
    const float* frontier       = (const float*)d_in[1];
    const float* rh             = (const float*)d_in[2];
    const float* fh             = (const float*)d_in[3];
    const float* robot_frontier = (const float*)d_in[4];
    const float* robot_past     = (const float*)d_in[5];
    const float* frontier_past  = (const float*)d_in[6];
    const float* Wq  = (const float*)d_in[7];  const float* bq  = (const float*)d_in[8];
    const float* Wk  = (const float*)d_in[9];  const float* bk  = (const float*)d_in[10];
    const float* Wv  = (const float*)d_in[11]; const float* bv  = (const float*)d_in[12];
    const float* Wn1 = (const float*)d_in[13]; const float* bn1 = (const float*)d_in[14];
    const float* Wn2 = (const float*)d_in[15]; const float* bn2 = (const float*)d_in[16];
    const float* We1 = (const float*)d_in[17]; const float* be1 = (const float*)d_in[18];
    const float* We2 = (const float*)d_in[19];

    float* out = (float*)d_out;
    float* out_robot    = out;            // 32*32*32   = 32768
    float* out_frontier = out + 32768;    // 32*128*32  = 131072
    float* out_rh       = out + 163840;   // 32*64*32   = 65536
    float* out_fh       = out + 229376;   // 32*64*32   = 65536
    float* out_edge     = out + 294912;   // 32*32*128  = 131072

    float* W = (float*)d_ws;
    float* robot1 = W;                 // 32768
    float* robot2 = W + 32768;         // 32768
    float* nf     = W + 65536;         // 131072
    float* w5     = W + 196608;        // 524288 (wT layout)
    float* yv5    = W + 720896;        // 65536
    float* w6     = W + 786432;        // 524288 (wT layout)
    float* yv6    = W + 1310720;       // 65536
    float* w7     = W + 1376256;       // 1048576 (wT layout)
    float* yv7    = W + 2424832;       // 131072

    // A: four intra-attentions (288 blocks, factorized K/V, no tail)
    intra_kernel<<<288, 256, 0, stream>>>(robot, frontier, rh, fh,
        Wq, bq, Wk, bk, Wv, bv, Wn1, bn1, Wn2, bn2,
        robot1, out_frontier, out_rh, out_fh);

    // B: y-side precompute for inter5 (y=rh1) and inter6 (y=fh1)
    pre_y_kernel<<<512, 256, 0, stream>>>(
        out_rh, NHh, w5, yv5, BATCH * NHh / 8,
        out_fh, NFHh, w6, yv6,
        Wk, bk, Wv, bv, We1);

    // C: inter5 (robot1 x rh1) + inter6 (frontier1 x fh1, fused pre_y7 tail)
    inter_main_kernel<<<1280, 256, 0, stream>>>(
        robot1, NRr, w5, yv5, NHh, robot_past, robot2,
        (float*)nullptr, (float*)nullptr, (float*)nullptr, BATCH * (NRr / TI),
        out_frontier, NFf, w6, yv6, NFHh, frontier_past, nf,
        (float*)nullptr, w7, yv7,
        Wq, bq, Wk, bk, Wv, bv, We1, be1, We2, Wn1, bn1, Wn2, bn2);

    // D: inter7 (robot2 x new_frontier) -> final robot + edge
    inter_main_kernel<<<256, 256, 0, stream>>>(
        robot2, NRr, w7, yv7, NFf, robot_frontier, out_robot, out_edge,
        (float*)nullptr, (float*)nullptr, BATCH * (NRr / TI),
        robot2, NRr, w7, yv7, NFf, robot_frontier, out_robot, out_edge,
        (float*)nullptr, (float*)nullptr,
        Wq, bq, Wk, bk, Wv, bv, We1, be1, We2, Wn1, bn1, Wn2, bn2);
}

// Round 17
// 197.714 us; speedup vs baseline: 1.2603x; 1.0317x over previous
//
#include <hip/hip_runtime.h>

#define BATCH 32
#define NRr 32
#define NFf 128
#define NHh 64
#define NFHh 64
#define TI 4

__device__ __forceinline__ float dot4(float4 a, float4 b) {
    return fmaf(a.x, b.x, fmaf(a.y, b.y, fmaf(a.z, b.z, a.w * b.w)));
}

// ---------------------------------------------------------------------------
// intra v9 (R16 exact, factorized): score_rj = (Wk^T q_r)·x_j; agg_r =
// Wv·(e_r@x) + bv. 288 blocks, CH=32, LDS 50.2 KB, no pre tail.
// ---------------------------------------------------------------------------
__global__ __launch_bounds__(256) void intra_kernel(
    const float* __restrict__ robot, const float* __restrict__ frontier,
    const float* __restrict__ rhist, const float* __restrict__ fhist,
    const float* __restrict__ Wq, const float* __restrict__ bq,
    const float* __restrict__ Wk, const float* __restrict__ bk,
    const float* __restrict__ Wv, const float* __restrict__ bv,
    const float* __restrict__ Wn1, const float* __restrict__ bn1,
    const float* __restrict__ Wn2, const float* __restrict__ bn2,
    float* __restrict__ o_robot, float* __restrict__ o_frontier,
    float* __restrict__ o_rh, float* __restrict__ o_fh)
{
    __shared__ __align__(16) float sXc[1024];
    __shared__ __align__(16) float sQ[1024];
    __shared__ __align__(16) float sQK[1024];
    __shared__ __align__(16) float sAgg[1024];
    __shared__ __align__(16) float sBig[8448];
    float* sS  = sBig;           // scores, pitch P = N+4
    float* sXT = sBig + 4224;    // x^T, pitch P2 = N+1
    float* sT  = sBig;           // T overlays after z phase

    const int blk = blockIdx.x, tid = threadIdx.x;
    const float* xin; float* xout; int N, lgN, b, chunk;
    if (blk < 32)       { xin=robot;    xout=o_robot;    N=32;  lgN=5; b=blk;          chunk=0; }
    else if (blk < 160) { xin=frontier; xout=o_frontier; N=128; lgN=7; b=(blk-32)>>2;  chunk=(blk-32)&3; }
    else if (blk < 224) { xin=rhist;    xout=o_rh;       N=64;  lgN=6; b=(blk-160)>>1; chunk=(blk-160)&1; }
    else                { xin=fhist;    xout=o_fh;       N=64;  lgN=6; b=(blk-224)>>1; chunk=(blk-224)&1; }

    const int P = N + 4, P2 = N + 1;
    const float* xb = xin + (size_t)b * N * 32;
    const int r0 = chunk << 5;
    const int d = tid & 31;

    {
        int idx = tid;
        #pragma unroll
        for (int it = 0; it < 4; ++it, idx += 256)
            sXc[idx] = xb[(r0 << 5) + idx];
    }
    for (int idx = tid; idx < (N << 5); idx += 256) {
        int j = idx >> 5, d2 = idx & 31;
        sXT[d2 * P2 + j] = xb[idx];
    }
    __syncthreads();

    {
        const float4* wq4 = (const float4*)(Wq + (d << 5));
        float4 wq[8];
        #pragma unroll
        for (int k = 0; k < 8; ++k) wq[k] = wq4[k];
        const float bqd = bq[d];
        int idx = tid;
        #pragma unroll
        for (int it = 0; it < 4; ++it, idx += 256) {
            int r = idx >> 5;
            const float4* xr = (const float4*)(sXc + (r << 5));
            float a = bqd;
            #pragma unroll
            for (int k = 0; k < 8; ++k) a += dot4(wq[k], xr[k]);
            sQ[idx] = a;
        }
    }
    __syncthreads();

    {
        int idx = tid;
        #pragma unroll
        for (int it = 0; it < 4; ++it, idx += 256) {
            int r = idx >> 5, e = idx & 31;
            const float* qr = sQ + (r << 5);
            float a = 0.f;
            #pragma unroll
            for (int dd2 = 0; dd2 < 32; ++dd2)
                a = fmaf(Wk[dd2 * 32 + e], qr[dd2], a);
            sQK[idx] = a;
        }
    }
    __syncthreads();

    for (int idx = tid; idx < (N << 5); idx += 256) {
        int r = idx >> lgN, j = idx & (N - 1);
        const float* qr = sQK + (r << 5);
        float a = 0.f;
        #pragma unroll
        for (int e = 0; e < 32; ++e) a = fmaf(qr[e], sXT[e * P2 + j], a);
        sS[r * P + j] = a;
    }
    __syncthreads();

    {
        int r = tid >> 3, l = tid & 7;
        float* row = sS + r * P;
        float m = -1e30f;
        for (int j = l; j < N; j += 8) m = fmaxf(m, row[j]);
        m = fmaxf(m, __shfl_xor(m, 4));
        m = fmaxf(m, __shfl_xor(m, 2));
        m = fmaxf(m, __shfl_xor(m, 1));
        float s = 0.f;
        for (int j = l; j < N; j += 8) { float ev = __expf(row[j] - m); row[j] = ev; s += ev; }
        s += __shfl_xor(s, 4); s += __shfl_xor(s, 2); s += __shfl_xor(s, 1);
        float inv = 1.0f / s;
        for (int j = l; j < N; j += 8) row[j] *= inv;
    }
    __syncthreads();

    {
        int idx = tid;
        #pragma unroll
        for (int it = 0; it < 4; ++it, idx += 256) {
            int r = idx >> 5, d2 = idx & 31;
            const float* er = sS + r * P;
            const float* xtr = sXT + d2 * P2;
            float a = 0.f;
            for (int j = 0; j < N; ++j) a = fmaf(er[j], xtr[j], a);
            sQ[idx] = a;
        }
    }
    __syncthreads();

    {
        const float4* wv4 = (const float4*)(Wv + (d << 5));
        float4 wv[8];
        #pragma unroll
        for (int k = 0; k < 8; ++k) wv[k] = wv4[k];
        const float bvd = bv[d];
        int idx = tid;
        #pragma unroll
        for (int it = 0; it < 4; ++it, idx += 256) {
            int r = idx >> 5;
            const float4* zr = (const float4*)(sQ + (r << 5));
            float a = bvd;
            #pragma unroll
            for (int k = 0; k < 8; ++k) a += dot4(wv[k], zr[k]);
            sAgg[idx] = a;
        }
    }
    __syncthreads();

    {
        const float4* w14 = (const float4*)(Wn1 + (tid << 6));
        float4 w1r[16];
        #pragma unroll
        for (int k = 0; k < 16; ++k) w1r[k] = w14[k];
        const float b1 = bn1[tid];
        for (int r = 0; r < 32; ++r) {
            const float4* xr = (const float4*)(sXc + (r << 5));
            const float4* ar = (const float4*)(sAgg + (r << 5));
            float a = b1;
            #pragma unroll
            for (int k = 0; k < 8; ++k) a += dot4(w1r[k], xr[k]);
            #pragma unroll
            for (int k = 0; k < 8; ++k) a += dot4(w1r[8 + k], ar[k]);
            sT[(r << 8) + tid] = fmaxf(a, 0.f);
        }
    }
    __syncthreads();

    {
        const int rg = tid >> 5;
        float acc[4] = {0.f, 0.f, 0.f, 0.f};
        #pragma unroll
        for (int hc = 0; hc < 4; ++hc) {
            const float4* w24 = (const float4*)(Wn2 + (d << 8) + (hc << 6));
            float4 w2r[16];
            #pragma unroll
            for (int k = 0; k < 16; ++k) w2r[k] = w24[k];
            #pragma unroll
            for (int p = 0; p < 4; ++p) {
                int r = rg + (p << 3);
                const float4* tr = (const float4*)(sT + (r << 8) + (hc << 6));
                float a = 0.f;
                #pragma unroll
                for (int k = 0; k < 16; ++k) a += dot4(w2r[k], tr[k]);
                acc[p] += a;
            }
        }
        const float b2 = bn2[d];
        #pragma unroll
        for (int p = 0; p < 4; ++p) {
            int r = rg + (p << 3);
            xout[((size_t)b * N << 5) + ((r0 + r) << 5) + d] = sXc[(r << 5) + d] + b2 + acc[p];
        }
    }
}

// ---------------------------------------------------------------------------
// pre_y: blocks [0,ghBase) = R16-exact y-side precompute (w via yk — cannot
// use H: same-launch, no ordering). Blocks [ghBase, ghBase+32): compute the
// fused matrices for the INTER launches:
//   G = We1[:,:32]·Wq (256x32), g = We1[:,:32]·bq + be1
//   H = We1[:,32:64]·Wk        , hb = We1[:,32:64]·bk
// ---------------------------------------------------------------------------
__global__ __launch_bounds__(256) void pre_y_kernel(
    const float* __restrict__ yA, int NyA, float* __restrict__ wOutA, float* __restrict__ yvOutA, int nBlkA,
    const float* __restrict__ yB, int NyB, float* __restrict__ wOutB, float* __restrict__ yvOutB,
    int ghBase,
    const float* __restrict__ Wq, const float* __restrict__ bq,
    const float* __restrict__ Wk, const float* __restrict__ bk,
    const float* __restrict__ Wv, const float* __restrict__ bv,
    const float* __restrict__ We1, const float* __restrict__ be1,
    float* __restrict__ Gm, float* __restrict__ gvec,
    float* __restrict__ Hm, float* __restrict__ hbvec)
{
    __shared__ __align__(16) float sY[256], sK[256];
    const int blk = blockIdx.x, tid = threadIdx.x;

    if (blk >= ghBase) {   // G/H fused-matrix blocks
        const int hr = ((blk - ghBase) << 3) + (tid >> 5), e = tid & 31;
        const float* w1q = We1 + hr * 65;
        const float* w1k = w1q + 32;
        float aG = 0.f, aH = 0.f;
        #pragma unroll
        for (int d2 = 0; d2 < 32; ++d2) {
            aG = fmaf(w1q[d2], Wq[d2 * 32 + e], aG);
            aH = fmaf(w1k[d2], Wk[d2 * 32 + e], aH);
        }
        Gm[(hr << 5) + e] = aG;
        Hm[(hr << 5) + e] = aH;
        if (e == 0) {
            float ag = be1[hr], ahb = 0.f;
            #pragma unroll
            for (int d2 = 0; d2 < 32; ++d2) {
                ag  = fmaf(w1q[d2], bq[d2], ag);
                ahb = fmaf(w1k[d2], bk[d2], ahb);
            }
            gvec[hr] = ag;
            hbvec[hr] = ahb;
        }
        return;
    }

    const float* y; int Ny; float* wOut; float* yvOut; int idx;
    if (blk < nBlkA) { y=yA; Ny=NyA; wOut=wOutA; yvOut=yvOutA; idx=blk; }
    else             { y=yB; Ny=NyB; wOut=wOutB; yvOut=yvOutB; idx=blk-nBlkA; }
    const int chunks = Ny >> 3;
    const int b = idx / chunks, j0 = (idx - b * chunks) << 3;

    sY[tid] = y[((size_t)(b * Ny + j0)) * 32 + tid];
    __syncthreads();

    {
        int jl = tid >> 5, dd = tid & 31;
        const float4* wk4 = (const float4*)(Wk + (dd << 5));
        const float4* wv4 = (const float4*)(Wv + (dd << 5));
        const float4* yr = (const float4*)(sY + (jl << 5));
        float aK = bk[dd], aV = bv[dd];
        #pragma unroll
        for (int k = 0; k < 8; ++k) {
            float4 yv4 = yr[k];
            aK += dot4(wk4[k], yv4);
            aV += dot4(wv4[k], yv4);
        }
        sK[(jl << 5) + dd] = aK;
        yvOut[((size_t)(b * Ny + j0 + jl)) * 32 + dd] = aV;
    }
    __syncthreads();

    {
        const float* w1 = We1 + tid * 65 + 32;
        float acc[8] = {0,0,0,0,0,0,0,0};
        #pragma unroll
        for (int e = 0; e < 32; ++e) {
            float we = w1[e];
            #pragma unroll
            for (int jl = 0; jl < 8; ++jl)
                acc[jl] = fmaf(we, sK[(jl << 5) + e], acc[jl]);
        }
        float* wbase = wOut + (((size_t)b * 64 + (tid >> 2)) * Ny + j0) * 4 + (tid & 3);
        #pragma unroll
        for (int jl = 0; jl < 8; ++jl)
            wbase[jl << 2] = acc[jl];
    }
}

// ---------------------------------------------------------------------------
// inter v8: G-fused u (no Q phase), partial-reduce merged into softmax,
// H-fused pre-tail (no yk sub-phase). Otherwise R16-proven structure.
// wT layout: ((b*64+h/4)*Ny + j)*4 + h%4.
// ---------------------------------------------------------------------------
__global__ __launch_bounds__(256) void inter_main_kernel(
    const float* __restrict__ xA, int NxA, const float* __restrict__ wA, const float* __restrict__ yvA,
    int NyA, const float* __restrict__ disA, float* __restrict__ outA, float* __restrict__ eA,
    float* __restrict__ wPreA, float* __restrict__ yvPreA, int nBlkA,
    const float* __restrict__ xB, int NxB, const float* __restrict__ wB, const float* __restrict__ yvB,
    int NyB, const float* __restrict__ disB, float* __restrict__ outB, float* __restrict__ eB,
    float* __restrict__ wPreB, float* __restrict__ yvPreB,
    const float* __restrict__ Gm, const float* __restrict__ gvec,
    const float* __restrict__ Hm, const float* __restrict__ hbvec,
    const float* __restrict__ Wv, const float* __restrict__ bv,
    const float* __restrict__ We1, const float* __restrict__ We2,
    const float* __restrict__ Wn1, const float* __restrict__ bn1,
    const float* __restrict__ Wn2, const float* __restrict__ bn2)
{
    __shared__ __align__(16) float sX[128];
    __shared__ __align__(16) float sQ[128];      // out rows for tail
    __shared__ __align__(16) float sAgg[128];
    __shared__ __align__(16) float sDis[512];    // [4][128]
    __shared__ __align__(16) float sC[256];
    __shared__ __align__(16) float sW2[256];
    __shared__ __align__(16) float sS[512];      // e values
    __shared__ __align__(16) float sUT[1024];    // u (ph2-3), then T (ph7-8)
    __shared__ __align__(16) float sPR[2048];    // partials (ph3), red (ph8)
    __shared__ __align__(16) float sYV[4096];    // yv tile [Ny][32]

    const int blk = blockIdx.x, tid = threadIdx.x;
    const float* x; int Nx; const float* w; const float* yv; int Ny;
    const float* dis; float* outp; float* ep; float* wPre; float* yvPre; int idx;
    if (blk < nBlkA) { x=xA; Nx=NxA; w=wA; yv=yvA; Ny=NyA; dis=disA; outp=outA; ep=eA; wPre=wPreA; yvPre=yvPreA; idx=blk; }
    else             { x=xB; Nx=NxB; w=wB; yv=yvB; Ny=NyB; dis=disB; outp=outB; ep=eB; wPre=wPreB; yvPre=yvPreB; idx=blk-nBlkA; }
    const int lgNy = (Ny == 128) ? 7 : 6;
    const int tiles = Nx >> 2;
    const int b = idx / tiles, i0 = (idx - b * tiles) << 2;
    const float* xrow = x + ((size_t)(b * Nx + i0)) * 32;

    // phase 0: stage x, dis, yv
    if (tid < 128) sX[tid] = xrow[tid];
    if (tid < Ny) {
        int il = tid >> (lgNy - 2), jq = tid & ((Ny >> 2) - 1);
        ((float4*)sDis)[(il << 5) + jq] =
            ((const float4*)(dis + ((size_t)(b * Nx + i0 + il)) * Ny))[jq];
    }
    {
        const float4* yv4 = (const float4*)(yv + ((size_t)(b * Ny) << 5));
        for (int k = tid; k < (Ny << 3); k += 256)
            ((float4*)sYV)[k] = yv4[k];
    }
    __syncthreads();

    // phase 2 (G-fused): u = G x + g ; c, w2
    {
        const float* grow = Gm + (tid << 5);
        const float g0 = gvec[tid];
        float acc[TI];
        #pragma unroll
        for (int il = 0; il < TI; ++il) acc[il] = g0;
        #pragma unroll
        for (int e = 0; e < 32; ++e) {
            float we = grow[e];
            #pragma unroll
            for (int il = 0; il < TI; ++il)
                acc[il] = fmaf(we, sX[(il << 5) + e], acc[il]);
        }
        #pragma unroll
        for (int il = 0; il < TI; ++il) sUT[(il << 8) + tid] = acc[il];
        sC[tid] = We1[tid * 65 + 64];
        sW2[tid] = We2[tid];
    }
    __syncthreads();

    // phase 3: scores; wave wv owns h-quarter, lane = j, all 4 i's
    const int wv = tid >> 6, lane = tid & 63;
    {
        const int hc0 = wv << 4;
        const float4* wT4 = (const float4*)w + (size_t)(b * 64) * Ny;
        const float4* c4p = (const float4*)sC;
        const float4* p4p = (const float4*)sW2;
        if (Ny == 64) {
            float dv[TI];
            #pragma unroll
            for (int il = 0; il < TI; ++il) dv[il] = sDis[(il << 7) + lane];
            float acc[TI] = {0.f, 0.f, 0.f, 0.f};
            #pragma unroll
            for (int t = 0; t < 16; ++t) {
                int hc = hc0 + t;
                float4 w4 = wT4[((size_t)hc << 6) + lane];
                float4 c4 = c4p[hc], p4 = p4p[hc];
                #pragma unroll
                for (int il = 0; il < TI; ++il) {
                    float4 u4 = ((const float4*)(sUT + (il << 8)))[hc];
                    acc[il] = fmaf(p4.x, fmaxf(fmaf(c4.x, dv[il], u4.x + w4.x), 0.f), acc[il]);
                    acc[il] = fmaf(p4.y, fmaxf(fmaf(c4.y, dv[il], u4.y + w4.y), 0.f), acc[il]);
                    acc[il] = fmaf(p4.z, fmaxf(fmaf(c4.z, dv[il], u4.z + w4.z), 0.f), acc[il]);
                    acc[il] = fmaf(p4.w, fmaxf(fmaf(c4.w, dv[il], u4.w + w4.w), 0.f), acc[il]);
                }
            }
            #pragma unroll
            for (int il = 0; il < TI; ++il)
                sPR[(wv << 9) + (il << 7) + lane] = acc[il];
        } else {
            float dv0[TI], dv1[TI];
            #pragma unroll
            for (int il = 0; il < TI; ++il) {
                dv0[il] = sDis[(il << 7) + lane];
                dv1[il] = sDis[(il << 7) + 64 + lane];
            }
            float acc0[TI] = {0.f, 0.f, 0.f, 0.f};
            float acc1[TI] = {0.f, 0.f, 0.f, 0.f};
            #pragma unroll
            for (int t = 0; t < 16; ++t) {
                int hc = hc0 + t;
                float4 wa = wT4[((size_t)hc << 7) + lane];
                float4 wb = wT4[((size_t)hc << 7) + 64 + lane];
                float4 c4 = c4p[hc], p4 = p4p[hc];
                #pragma unroll
                for (int il = 0; il < TI; ++il) {
                    float4 u4 = ((const float4*)(sUT + (il << 8)))[hc];
                    acc0[il] = fmaf(p4.x, fmaxf(fmaf(c4.x, dv0[il], u4.x + wa.x), 0.f), acc0[il]);
                    acc0[il] = fmaf(p4.y, fmaxf(fmaf(c4.y, dv0[il], u4.y + wa.y), 0.f), acc0[il]);
                    acc0[il] = fmaf(p4.z, fmaxf(fmaf(c4.z, dv0[il], u4.z + wa.z), 0.f), acc0[il]);
                    acc0[il] = fmaf(p4.w, fmaxf(fmaf(c4.w, dv0[il], u4.w + wa.w), 0.f), acc0[il]);
                    acc1[il] = fmaf(p4.x, fmaxf(fmaf(c4.x, dv1[il], u4.x + wb.x), 0.f), acc1[il]);
                    acc1[il] = fmaf(p4.y, fmaxf(fmaf(c4.y, dv1[il], u4.y + wb.y), 0.f), acc1[il]);
                    acc1[il] = fmaf(p4.z, fmaxf(fmaf(c4.z, dv1[il], u4.z + wb.z), 0.f), acc1[il]);
                    acc1[il] = fmaf(p4.w, fmaxf(fmaf(c4.w, dv1[il], u4.w + wb.w), 0.f), acc1[il]);
                }
            }
            #pragma unroll
            for (int il = 0; il < TI; ++il) {
                sPR[(wv << 9) + (il << 7) + lane] = acc0[il];
                sPR[(wv << 9) + (il << 7) + 64 + lane] = acc1[il];
            }
        }
    }
    __syncthreads();

    // phase 4 (merged reduce + softmax): wave wv handles row wv
    {
        const int base = (wv << 7) + lane;
        float v0 = sPR[base] + sPR[512 + base] + sPR[1024 + base] + sPR[1536 + base];
        float v1 = -1e30f;
        if (Ny == 128) {
            const int b2 = base + 64;
            v1 = sPR[b2] + sPR[512 + b2] + sPR[1024 + b2] + sPR[1536 + b2];
        }
        float m = fmaxf(v0, v1);
        #pragma unroll
        for (int msk = 32; msk; msk >>= 1) m = fmaxf(m, __shfl_xor(m, msk));
        float e0 = __expf(v0 - m);
        float e1 = (Ny == 128) ? __expf(v1 - m) : 0.f;
        float s = e0 + e1;
        #pragma unroll
        for (int msk = 32; msk; msk >>= 1) s += __shfl_xor(s, msk);
        float inv = 1.0f / s;
        e0 *= inv; e1 *= inv;
        sS[base] = e0;
        if (Ny == 128) sS[base + 64] = e1;
        if (ep) {
            float* erow = ep + ((size_t)(b * Nx + i0 + wv)) * Ny;
            erow[lane] = e0;
            if (Ny == 128) erow[64 + lane] = e1;
        }
    }

    // phase 5: agg = e @ yv (LDS); same wave as softmax row — no barrier
    {
        const int dd = lane & 31, jg = lane >> 5;
        float p = 0.f;
        for (int j = jg; j < Ny; j += 2)
            p = fmaf(sS[(wv << 7) + j], sYV[(j << 5) + dd], p);
        p += __shfl_xor(p, 32);
        if (jg == 0) sAgg[(wv << 5) + dd] = p;
    }
    __syncthreads();

    // phase 7: node-MLP hidden (T overlays u)
    {
        const float4* w14 = (const float4*)(Wn1 + (tid << 6));
        const float b1 = bn1[tid];
        float acc[TI];
        #pragma unroll
        for (int il = 0; il < TI; ++il) acc[il] = b1;
        #pragma unroll
        for (int k = 0; k < 8; ++k) {
            float4 wa = w14[k];
            #pragma unroll
            for (int il = 0; il < TI; ++il)
                acc[il] += dot4(wa, ((const float4*)(sX + (il << 5)))[k]);
        }
        #pragma unroll
        for (int k = 0; k < 8; ++k) {
            float4 wb = w14[8 + k];
            #pragma unroll
            for (int il = 0; il < TI; ++il)
                acc[il] += dot4(wb, ((const float4*)(sAgg + (il << 5)))[k]);
        }
        __syncthreads();
        #pragma unroll
        for (int il = 0; il < TI; ++il) sUT[(il << 8) + tid] = fmaxf(acc[il], 0.f);
    }
    __syncthreads();

    // phase 8: out = x + T @ Wn2^T + bn2
    {
        const int hg = tid >> 5, dd = tid & 31;
        const float4* w24 = (const float4*)(Wn2 + (dd << 8) + (hg << 5));
        float4 w2r[8];
        #pragma unroll
        for (int k = 0; k < 8; ++k) w2r[k] = w24[k];
        float p[TI] = {0.f, 0.f, 0.f, 0.f};
        #pragma unroll
        for (int k = 0; k < 8; ++k) {
            #pragma unroll
            for (int il = 0; il < TI; ++il)
                p[il] += dot4(w2r[k], ((const float4*)(sUT + (il << 8) + (hg << 5)))[k]);
        }
        #pragma unroll
        for (int il = 0; il < TI; ++il) sPR[(hg << 7) + (il << 5) + dd] = p[il];
    }
    __syncthreads();
    if (tid < 128) {
        int il = tid >> 5, dd = tid & 31;
        float a = bn2[dd] + sX[tid];
        #pragma unroll
        for (int hg = 0; hg < 8; ++hg) a += sPR[(hg << 7) + tid];
        outp[((size_t)(b * Nx + i0 + il)) * 32 + dd] = a;
        if (wPre) sQ[tid] = a;     // keep out rows for tail
    }

    // ---- H-fused pre tail (stage-6 blocks): w/yv for the next stage ----
    if (wPre) {
        __syncthreads();
        if (tid < 128) {           // yv = Wv out + bv
            int il = tid >> 5, dd = tid & 31;
            const float4* wm4 = (const float4*)(Wv + (dd << 5));
            const float4* orow = (const float4*)(sQ + (il << 5));
            float a = bv[dd];
            #pragma unroll
            for (int k = 0; k < 8; ++k) a += dot4(wm4[k], orow[k]);
            yvPre[(((size_t)(b * Nx + i0 + il)) << 5) + dd] = a;
        }
        {                          // w = H out + hb (no yk round-trip)
            const float* hrow = Hm + (tid << 5);
            const float hb0 = hbvec[tid];
            float acc[4];
            #pragma unroll
            for (int il = 0; il < 4; ++il) acc[il] = hb0;
            #pragma unroll
            for (int e = 0; e < 32; ++e) {
                float we = hrow[e];
                #pragma unroll
                for (int il = 0; il < 4; ++il)
                    acc[il] = fmaf(we, sQ[(il << 5) + e], acc[il]);
            }
            float* wbase = wPre + (((size_t)b * 64 + (tid >> 2)) * Nx + i0) * 4 + (tid & 3);
            #pragma unroll
            for (int il = 0; il < 4; ++il)
                wbase[il << 2] = acc[il];
        }
    }
}

// ---------------------------------------------------------------------------
extern "C" void kernel_launch(void* const* d_in, const int* in_sizes, int n_in,
                              void* d_out, int out_size, void* d_ws, size_t ws_size,
                              hipStream_t stream) {
    const float* robot          = (const float*)d_in[0];
    const float* frontier       = (const float*)d_in[1];
    const float* rh             = (const float*)d_in[2];
    const float* fh             = (const float*)d_in[3];
    const float* robot_frontier = (const float*)d_in[4];
    const float* robot_past     = (const float*)d_in[5];
    const float* frontier_past  = (const float*)d_in[6];
    const float* Wq  = (const float*)d_in[7];  const float* bq  = (const float*)d_in[8];
    const float* Wk  = (const float*)d_in[9];  const float* bk  = (const float*)d_in[10];
    const float* Wv  = (const float*)d_in[11]; const float* bv  = (const float*)d_in[12];
    const float* Wn1 = (const float*)d_in[13]; const float* bn1 = (const float*)d_in[14];
    const float* Wn2 = (const float*)d_in[15]; const float* bn2 = (const float*)d_in[16];
    const float* We1 = (const float*)d_in[17]; const float* be1 = (const float*)d_in[18];
    const float* We2 = (const float*)d_in[19];

    float* out = (float*)d_out;
    float* out_robot    = out;            // 32*32*32   = 32768
    float* out_frontier = out + 32768;    // 32*128*32  = 131072
    float* out_rh       = out + 163840;   // 32*64*32   = 65536
    float* out_fh       = out + 229376;   // 32*64*32   = 65536
    float* out_edge     = out + 294912;   // 32*32*128  = 131072

    float* W = (float*)d_ws;
    float* robot1 = W;                 // 32768
    float* robot2 = W + 32768;         // 32768
    float* nf     = W + 65536;         // 131072
    float* w5     = W + 196608;        // 524288 (wT layout)
    float* yv5    = W + 720896;        // 65536
    float* w6     = W + 786432;        // 524288 (wT layout)
    float* yv6    = W + 1310720;       // 65536
    float* w7     = W + 1376256;       // 1048576 (wT layout)
    float* yv7    = W + 2424832;       // 131072 -> 2555904
    float* Gm     = W + 2555904;       // 8192
    float* gvec   = W + 2564096;       // 256
    float* Hm     = W + 2564352;       // 8192
    float* hbvec  = W + 2572544;       // 256 -> ends 2572800

    // A: four intra-attentions (288 blocks, factorized K/V, no tail)
    intra_kernel<<<288, 256, 0, stream>>>(robot, frontier, rh, fh,
        Wq, bq, Wk, bk, Wv, bv, Wn1, bn1, Wn2, bn2,
        robot1, out_frontier, out_rh, out_fh);

    // B: pre_y for inter5/inter6 + G/H fused-matrix blocks (512 + 32)
    pre_y_kernel<<<544, 256, 0, stream>>>(
        out_rh, NHh, w5, yv5, BATCH * NHh / 8,
        out_fh, NFHh, w6, yv6,
        512,
        Wq, bq, Wk, bk, Wv, bv, We1, be1,
        Gm, gvec, Hm, hbvec);

    // C: inter5 (robot1 x rh1) + inter6 (frontier1 x fh1, H-fused pre7 tail)
    inter_main_kernel<<<1280, 256, 0, stream>>>(
        robot1, NRr, w5, yv5, NHh, robot_past, robot2,
        (float*)nullptr, (float*)nullptr, (float*)nullptr, BATCH * (NRr / TI),
        out_frontier, NFf, w6, yv6, NFHh, frontier_past, nf,
        (float*)nullptr, w7, yv7,
        Gm, gvec, Hm, hbvec, Wv, bv, We1, We2, Wn1, bn1, Wn2, bn2);

    // D: inter7 (robot2 x new_frontier) -> final robot + edge
    inter_main_kernel<<<256, 256, 0, stream>>>(
        robot2, NRr, w7, yv7, NFf, robot_frontier, out_robot, out_edge,
        (float*)nullptr, (float*)nullptr, BATCH * (NRr / TI),
        robot2, NRr, w7, yv7, NFf, robot_frontier, out_robot, out_edge,
        (float*)nullptr, (float*)nullptr,
        Gm, gvec, Hm, hbvec, Wv, bv, We1, We2, Wn1, bn1, Wn2, bn2);
}